// Round 6
// baseline (451.592 us; speedup 1.0000x reference)
//
#include <hip/hip_runtime.h>

#define BB 256
#define SS 16
#define II 64
#define DD 128
#define TT 65            // I + 1 (BOS prepended)
#define BOS_ID 100000
#define XROW 304         // padded x row stride (256 B data + 48 B pad)
#define XROWS 73         // 8 zero guard rows + 65 positions
#define XT (XROWS*XROW)  // 22192 B per tile

// ---------------- ws layout (bytes) ----------------
#define OFF_LEN  0                        // int lengths[B][S]            16384
#define OFF_ML   16384                    // int maxlen[S]                64
#define OFF_ME   32768                    // float mean_emb[B][S][D]      2 MB
#define OFF_HB   (32768 + 2097152)        // float hB[S][B][D]            2 MB
#define OFF_WB2  (OFF_HB + 2097152)       // bf16 wB2[80 chunks][2048]    327680
#define OFF_WIHP (OFF_WB2 + 327680)       // u32 wihP[64][384]            98304
#define OFF_WGRU (OFF_WIHP + 98304)       // u32 wgruP[64][512]           131072
#define OFF_GI   (OFF_WGRU + 131072)      // float gi[4096][384]          6291456

// ---------------- out layout (float elements) ----------------
#define OUT_MASK  (BB*SS*TT*DD)          // 34,078,720
#define OUT_UTYPE (OUT_MASK + BB*SS*TT)

typedef __attribute__((ext_vector_type(8))) short short8;
typedef __attribute__((ext_vector_type(4))) float f32x4;

__device__ __forceinline__ unsigned short f2bf(float f) {
    unsigned int u = __builtin_bit_cast(unsigned int, f);
    return (unsigned short)((u + 0x7fffu + ((u >> 16) & 1u)) >> 16);  // RNE
}
__device__ __forceinline__ float bf2f(unsigned short h) {
    unsigned int u = ((unsigned int)h) << 16;
    return __builtin_bit_cast(float, u);
}
__device__ __forceinline__ void gld16(const void* g, void* l) {
    __builtin_amdgcn_global_load_lds(
        (const __attribute__((address_space(1))) void*)g,
        (__attribute__((address_space(3))) void*)l, 16, 0, 0);
}

// ============ kernel 0: weight prep ============
// Conv + fusion weights -> wB2, 80 half-chunks of 4 KB; full chunk cid = 8 KB:
//   cid = (L*3+k)*4+cq for conv (0..35), 36+cq for fusion.
//   half (nh) layout [g 0..3][c 0..63][e 0..7] bf16: W[co=nh*64+c][ci=cq*32+g*8+e].
//   RESIDUAL TRICK: identity added to tap k=2 (off=0) of every conv layer,
//   so conv(x)+x is a single GEMM (epilogue never re-reads x).
// wih  -> wihP[dd][r]  (packed bf16 pairs), whh/fusB -> wgruP[dd][r].
__global__ __launch_bounds__(256) void prep_kernel(
    const float* __restrict__ w0, const float* __restrict__ w1,
    const float* __restrict__ w2, const float* __restrict__ fus_w,
    const float* __restrict__ wih, const float* __restrict__ whh,
    unsigned short* __restrict__ wB2,
    unsigned int* __restrict__ wihP, unsigned int* __restrict__ wgruP)
{
    int idx = blockIdx.x * 256 + threadIdx.x;
    if (idx < 163840) {
        int cid2  = idx >> 11;           // 0..79
        int inner = idx & 2047;
        int g = inner >> 9;
        int c = (inner >> 3) & 63;
        int e = inner & 7;
        int nh   = cid2 & 1;
        int rest = cid2 >> 1;            // 0..39
        int cq   = rest & 3;
        int m    = rest >> 2;            // 0..8 conv, 9 fusion
        int ci = cq * 32 + g * 8 + e;
        int co = nh * 64 + c;
        float v;
        if (m < 9) {
            int L = m / 3, k = m % 3;
            const float* w = (L == 0) ? w0 : ((L == 1) ? w1 : w2);
            v = w[(co * 128 + ci) * 3 + k];
            if (k == 2 && ci == co) v += 1.0f;   // fold residual into GEMM
        } else {
            v = fus_w[co * 256 + ci];    // tc half of fus_w
        }
        wB2[idx] = f2bf(v);
    } else if (idx < 163840 + 24576) {
        int f  = idx - 163840;
        int dd = f / 384;
        int r  = f % 384;
        unsigned int lo = f2bf(wih[r * 128 + 2 * dd]);
        unsigned int hi = f2bf(wih[r * 128 + 2 * dd + 1]);
        wihP[f] = (hi << 16) | lo;
    } else if (idx < 163840 + 24576 + 32768) {
        int f  = idx - 163840 - 24576;
        int dd = f >> 9;
        int r  = f & 511;
        float v0, v1;
        if (r < 384) { v0 = whh[r * 128 + 2 * dd]; v1 = whh[r * 128 + 2 * dd + 1]; }
        else { const float* fw = fus_w + (r - 384) * 256 + 128;
               v0 = fw[2 * dd]; v1 = fw[2 * dd + 1]; }
        wgruP[f] = ((unsigned int)f2bf(v1) << 16) | (unsigned int)f2bf(v0);
    }
}

// ============ kernel 1: lengths, per-s max, u_type ============
__global__ __launch_bounds__(256) void len_kernel(
    const int* __restrict__ item_id, const int* __restrict__ u_type,
    int* __restrict__ lengths, int* __restrict__ maxlen,
    float* __restrict__ u_out)
{
    int s = blockIdx.x;
    int b = threadIdx.x;
    const int* row = item_id + (b * SS + s) * II;
    int cnt = 0;
    for (int i = 0; i < II; ++i) cnt += (row[i] > 0);
    lengths[b * SS + s] = cnt;
    __shared__ int red[256];
    red[b] = cnt;
    __syncthreads();
    for (int off = 128; off > 0; off >>= 1) {
        if (b < off) red[b] = max(red[b], red[b + off]);
        __syncthreads();
    }
    if (b == 0) maxlen[s] = red[0];
    if (s == 0) u_out[b] = (float)u_type[b];
}

// ============ kernel 2: masks + mean_emb ============
__global__ __launch_bounds__(128) void mean_kernel(
    const int* __restrict__ item_id, const int* __restrict__ eval_from,
    const float* __restrict__ emb,
    const int* __restrict__ lengths, const int* __restrict__ maxlen,
    float* __restrict__ mean_emb, float* __restrict__ mask_out)
{
    int bid = blockIdx.x;
    int b = bid >> 4, s = bid & 15;
    int tid = threadIdx.x;
    __shared__ int seqs[TT];
    __shared__ int msk[TT];
    int ml  = maxlen[s];
    int len = lengths[bid];
    int ef  = eval_from[b];
    if (tid < TT) {
        int v;
        if (tid == 0) v = BOS_ID;
        else { int it = item_id[bid * II + tid - 1]; v = it > 0 ? it : 0; }
        if (tid > ml) v = 0;
        int m = (v != 0) && !(tid == len && len > 0);
        seqs[tid] = v;
        msk[tid]  = m;
        mask_out[bid * TT + tid] = (m && (s >= ef)) ? 1.0f : 0.0f;
    }
    __syncthreads();
    int cnt = 0;
    for (int p = 0; p < TT; ++p) cnt += msk[p];
    float acc = 0.0f;
    int d = tid;
    for (int p = 0; p < TT; ++p) {
        if (msk[p]) acc += emb[seqs[p] * DD + d];
    }
    mean_emb[bid * DD + d] = acc / (float)max(cnt, 1);
}

// ============ kernel 3a: gi = me @ wih^T + bih ============
__global__ __launch_bounds__(384, 1) void gi_kernel(
    const float* __restrict__ me_all, const unsigned int* __restrict__ wihP,
    const float* __restrict__ bih, float* __restrict__ gi_all)
{
    __shared__ __align__(16) unsigned int wl[64 * 384];   // 96 KB
    __shared__ __align__(16) float me[DD];
    int t   = threadIdx.x;
    int blk = blockIdx.x;
    {
        const unsigned char* g = (const unsigned char*)wihP + t * 16;
        unsigned char* l = (unsigned char*)wl + t * 16;
#pragma unroll
        for (int i = 0; i < 16; ++i) gld16(g + i * 6144, l + i * 6144);
    }
    float bi = bih[t];
    asm volatile("s_waitcnt vmcnt(0)" ::: "memory");
    __syncthreads();
    for (int q = 0; q < 16; ++q) {
        int bs = blk * 16 + q;
        if (t < DD) me[t] = me_all[bs * DD + t];
        __syncthreads();
        float acc = bi;
#pragma unroll
        for (int dd = 0; dd < 64; ++dd) {
            unsigned int u = wl[dd * 384 + t];
            float f0 = __builtin_bit_cast(float, u << 16);
            float f1 = __builtin_bit_cast(float, u & 0xffff0000u);
            acc += f0 * me[2 * dd] + f1 * me[2 * dd + 1];
        }
        gi_all[bs * 384 + t] = acc;
        __syncthreads();
    }
}

// ============ kernel 3b: sequential GRU (gh, hb) ============
__global__ __launch_bounds__(512, 1) void gru_kernel(
    const unsigned int* __restrict__ wgruP, const float* __restrict__ bhh,
    const float* __restrict__ fus_b, const float* __restrict__ gi_all,
    float* __restrict__ hB)
{
    __shared__ __align__(16) unsigned int wl[64 * 512];   // 128 KB
    __shared__ float h[DD];
    __shared__ float g_z[DD], g_inn[DD], g_hn[DD];
    int t = threadIdx.x;
    int b = blockIdx.x;
    int j = t & 127;
    int grp = t >> 7;      // 0=r, 1=z, 2=n, 3=hb
    {
        const unsigned char* g = (const unsigned char*)wgruP + t * 16;
        unsigned char* l = (unsigned char*)wl + t * 16;
#pragma unroll
        for (int i = 0; i < 16; ++i) gld16(g + i * 8192, l + i * 8192);
    }
    float bias = (t < 384) ? bhh[t] : fus_b[j];
    if (t < DD) h[t] = 0.0f;
    asm volatile("s_waitcnt vmcnt(0)" ::: "memory");
    __syncthreads();
    for (int s = 0; s < SS; ++s) {
        float gi = (grp < 3) ? gi_all[(b * SS + s) * 384 + t] : 0.0f;
        float acc = bias;
#pragma unroll
        for (int dd = 0; dd < 64; ++dd) {
            unsigned int u = wl[dd * 512 + t];
            float f0 = __builtin_bit_cast(float, u << 16);
            float f1 = __builtin_bit_cast(float, u & 0xffff0000u);
            acc += f0 * h[2 * dd] + f1 * h[2 * dd + 1];
        }
        if (grp == 3) {
            hB[(s * BB + b) * DD + j] = acc;          // h BEFORE update; fus_b included
        } else if (grp == 1) { g_z[j] = gi + acc; }
        else if (grp == 2)   { g_inn[j] = gi; g_hn[j] = acc; }
        __syncthreads();
        if (grp == 0) {
            float r = 1.0f / (1.0f + expf(-(gi + acc)));
            float z = 1.0f / (1.0f + expf(-g_z[j]));
            float n = tanhf(g_inn[j] + r * g_hn[j]);
            h[j] = (1.0f - z) * n + z * h[j];
        }
        __syncthreads();
    }
}

// ============ kernel 4: MFMA TCN + fusion (v5: whole tile per wave) ============
// 128 threads = 2 waves; wave wv owns tile (bid*2+wv) entirely: 5 M-tiles x
// 8 N-tiles of 16x16, acc[5][8]. Weight chunks (8 KB: 32 ci x 128 co) staged
// cooperatively into a shared ring-4 via global_load_lds, counted vmcnt(4),
// ONE barrier per chunk. Residual is folded into tap-2 weights (identity).
__global__ __launch_bounds__(128, 2) void tcn_kernel(
    const int* __restrict__ item_id, const float* __restrict__ emb,
    const int* __restrict__ maxlen,
    const unsigned short* __restrict__ wB2,
    const float* __restrict__ cb0, const float* __restrict__ cb1,
    const float* __restrict__ cb2,
    const float* __restrict__ hB, float* __restrict__ reps)
{
    __shared__ __align__(16) unsigned char lds_x[2][XT];   // 44384 B
    __shared__ __align__(16) unsigned char ring[4][8192];  // 32768 B
    __shared__ int seqs2[2][TT];

    const int tid = threadIdx.x, bid = blockIdx.x;
    const int lane = tid & 63, wv = tid >> 6;
    const int l15 = lane & 15, q4 = lane >> 4;
    const int tile = bid * 2 + wv;
    const int b = tile >> 4, s = tile & 15;

    const unsigned char* wbase = (const unsigned char*)wB2 + wv * 4096 + lane * 16;
    unsigned char* xb = lds_x[wv];

    // prologue: stage chunks 0,1 into ring slots 0,1 (each wave stages its half)
#pragma unroll
    for (int slot = 0; slot < 2; ++slot)
#pragma unroll
        for (int i = 0; i < 4; ++i)
            gld16(wbase + slot * 8192 + i * 1024, &ring[slot][wv * 4096 + i * 1024]);

    for (int idx = tid; idx < 2 * TT; idx += 128) {
        int tt = idx / TT, p = idx - tt * TT;
        int tl = bid * 2 + tt;
        int v;
        if (p == 0) v = BOS_ID;
        else { int it = item_id[tl * II + p - 1]; v = it > 0 ? it : 0; }
        if (p > maxlen[tl & 15]) v = 0;
        seqs2[tt][p] = v;
    }
    // zero guard rows 0..7 of both tiles (608 dwords each)
    for (int i = tid; i < 608; i += 128) {
        *(unsigned int*)(lds_x[0] + i * 4) = 0u;
        *(unsigned int*)(lds_x[1] + i * 4) = 0u;
    }
    __syncthreads();

    // gather embeddings for OWN tile -> rows 8..72 (bf16 pairs, padded rows)
#pragma unroll 4
    for (int p = 0; p < TT; ++p) {
        const float2 e = *((const float2*)(emb + (long)seqs2[wv][p] * DD) + lane);
        unsigned int pk = ((unsigned int)f2bf(e.y) << 16) | (unsigned int)f2bf(e.x);
        *(unsigned int*)(xb + (8 + p) * XROW + lane * 4) = pk;
    }

    f32x4 acc[5][8];

#pragma unroll 1
    for (int cid = 0; cid < 40; ++cid) {
        int L = 0, kq = 0, cq, off;
        if (cid < 36) { L = cid / 12; kq = cid - L * 12; int k = kq >> 2; cq = kq & 3; off = (2 - k) << L; }
        else { cq = cid - 36; off = 0; }
        if (cid == 36 || (cid < 36 && kq == 0)) {   // zero acc at layer/fusion START only
#pragma unroll
            for (int mt = 0; mt < 5; ++mt)
#pragma unroll
                for (int nt = 0; nt < 8; ++nt)
#pragma unroll
                    for (int r = 0; r < 4; ++r) acc[mt][nt][r] = 0.0f;
        }
        // my half of chunk cid has landed when <=4 of my loads are outstanding
        if (cid < 39) asm volatile("s_waitcnt vmcnt(4)" ::: "memory");
        else          asm volatile("s_waitcnt vmcnt(0)" ::: "memory");
        __syncthreads();   // other wave's half landed too; slot (cid+2)&3 free

        if (cid <= 37) {   // stage chunk cid+2
            const unsigned char* src = wbase + (size_t)(cid + 2) * 8192;
            unsigned char* dst = &ring[(cid + 2) & 3][wv * 4096];
#pragma unroll
            for (int i = 0; i < 4; ++i) gld16(src + i * 1024, dst + i * 1024);
        }

        const unsigned char* sb = &ring[cid & 3][0];
        short8 af[5];
#pragma unroll
        for (int mt = 0; mt < 5; ++mt)
            af[mt] = *(const short8*)(xb + (8 + mt * 16 + l15 - off) * XROW +
                                      cq * 64 + q4 * 16);
#pragma unroll
        for (int nt = 0; nt < 8; ++nt) {
            short8 bf = *(const short8*)(sb + (nt >> 2) * 4096 + q4 * 1024 +
                                         ((nt & 3) * 16 + l15) * 16);
#pragma unroll
            for (int mt = 0; mt < 5; ++mt)
                acc[mt][nt] = __builtin_amdgcn_mfma_f32_16x16x32_bf16(
                    af[mt], bf, acc[mt][nt], 0, 0, 0);
        }

        if (cid < 36 && kq == 11) {   // layer epilogue: relu(acc+bias) -> x (in place)
            const float* cb = (L == 0) ? cb0 : ((L == 1) ? cb1 : cb2);
#pragma unroll
            for (int nt = 0; nt < 8; ++nt) {
                float bia = cb[nt * 16 + l15];
#pragma unroll
                for (int mt = 0; mt < 5; ++mt)
#pragma unroll
                    for (int r = 0; r < 4; ++r) {
                        int p = mt * 16 + q4 * 4 + r;
                        if (p < TT) {
                            float v = acc[mt][nt][r] + bia;
                            *(unsigned short*)(xb + (8 + p) * XROW +
                                               (nt * 16 + l15) * 2) =
                                f2bf(v > 0.f ? v : 0.f);
                        }
                    }
            }
            asm volatile("s_waitcnt lgkmcnt(0)" ::: "memory");
            __builtin_amdgcn_sched_barrier(0);
        }
    }

    // fusion writeout: reps[p][j] = (p<=ml) ? acc + hb : 0
    const int ml = maxlen[s];
    const float* hbp = hB + (s * BB + b) * DD;
    float hb[8];
#pragma unroll
    for (int nt = 0; nt < 8; ++nt) hb[nt] = hbp[nt * 16 + l15];
    long ob = (long)tile * (TT * DD);
#pragma unroll
    for (int mt = 0; mt < 5; ++mt)
#pragma unroll
        for (int nt = 0; nt < 8; ++nt)
#pragma unroll
            for (int r = 0; r < 4; ++r) {
                int p = mt * 16 + q4 * 4 + r;
                if (p < TT) {
                    float v = (p <= ml) ? (acc[mt][nt][r] + hb[nt]) : 0.0f;
                    reps[ob + p * DD + nt * 16 + l15] = v;
                }
            }
}

extern "C" void kernel_launch(void* const* d_in, const int* in_sizes, int n_in,
                              void* d_out, int out_size, void* d_ws, size_t ws_size,
                              hipStream_t stream) {
    const int*   item_id   = (const int*)  d_in[0];
    const int*   eval_from = (const int*)  d_in[1];
    const int*   u_type    = (const int*)  d_in[2];
    const float* emb       = (const float*)d_in[3];
    const float* conv_w0   = (const float*)d_in[4];
    const float* conv_b0   = (const float*)d_in[5];
    const float* conv_w1   = (const float*)d_in[6];
    const float* conv_b1   = (const float*)d_in[7];
    const float* conv_w2   = (const float*)d_in[8];
    const float* conv_b2   = (const float*)d_in[9];
    const float* gru_wih   = (const float*)d_in[10];
    const float* gru_whh   = (const float*)d_in[11];
    const float* gru_bih   = (const float*)d_in[12];
    const float* gru_bhh   = (const float*)d_in[13];
    const float* fus_w     = (const float*)d_in[14];
    const float* fus_b     = (const float*)d_in[15];

    char* ws = (char*)d_ws;
    int*            lengths  = (int*)           (ws + OFF_LEN);
    int*            maxlen   = (int*)           (ws + OFF_ML);
    float*          mean_emb = (float*)         (ws + OFF_ME);
    float*          hB       = (float*)         (ws + OFF_HB);
    unsigned short* wB2      = (unsigned short*)(ws + OFF_WB2);
    unsigned int*   wihP     = (unsigned int*)  (ws + OFF_WIHP);
    unsigned int*   wgruP    = (unsigned int*)  (ws + OFF_WGRU);
    float*          gi_all   = (float*)         (ws + OFF_GI);

    float* out  = (float*)d_out;
    float* reps = out;
    float* mout = out + OUT_MASK;
    float* uout = out + OUT_UTYPE;

    prep_kernel<<<864, 256, 0, stream>>>(conv_w0, conv_w1, conv_w2, fus_w,
                                         gru_wih, gru_whh, wB2, wihP, wgruP);
    len_kernel<<<SS, 256, 0, stream>>>(item_id, u_type, lengths, maxlen, uout);
    mean_kernel<<<BB * SS, 128, 0, stream>>>(item_id, eval_from, emb, lengths, maxlen,
                                             mean_emb, mout);
    gi_kernel<<<BB, 384, 0, stream>>>(mean_emb, wihP, gru_bih, gi_all);
    gru_kernel<<<BB, 512, 0, stream>>>(wgruP, gru_bhh, fus_b, gi_all, hB);
    tcn_kernel<<<BB * SS / 2, 128, 0, stream>>>(item_id, emb, maxlen, wB2,
                                                conv_b0, conv_b1, conv_b2, hB, reps);
}

// Round 7
// 443.270 us; speedup vs baseline: 1.0188x; 1.0188x over previous
//
#include <hip/hip_runtime.h>

#define BB 256
#define SS 16
#define II 64
#define DD 128
#define TT 65            // I + 1 (BOS prepended)
#define BOS_ID 100000
#define XROW 256         // x row stride: 128 bf16, XOR-16B swizzled (no pad)
#define XROWS 73         // 8 zero guard rows + 65 positions
#define XT (XROWS*XROW)  // 18688 B per tile

// ---------------- ws layout (bytes) ----------------
#define OFF_LEN  0                        // int lengths[B][S]            16384
#define OFF_ML   16384                    // int maxlen[S]                64
#define OFF_ME   32768                    // float mean_emb[B][S][D]      2 MB
#define OFF_HB   (32768 + 2097152)        // float hB[S][B][D]            2 MB
#define OFF_WB2  (OFF_HB + 2097152)       // bf16 wB2[80 chunks][2048]    327680
#define OFF_WIHP (OFF_WB2 + 327680)       // u32 wihP[64][384]            98304
#define OFF_WGRU (OFF_WIHP + 98304)       // u32 wgruP[64][512]           131072
#define OFF_GI   (OFF_WGRU + 131072)      // float gi[4096][384]          6291456

// ---------------- out layout (float elements) ----------------
#define OUT_MASK  (BB*SS*TT*DD)          // 34,078,720
#define OUT_UTYPE (OUT_MASK + BB*SS*TT)

typedef __attribute__((ext_vector_type(8))) short short8;
typedef __attribute__((ext_vector_type(4))) float f32x4;

__device__ __forceinline__ unsigned short f2bf(float f) {
    unsigned int u = __builtin_bit_cast(unsigned int, f);
    return (unsigned short)((u + 0x7fffu + ((u >> 16) & 1u)) >> 16);  // RNE
}
__device__ __forceinline__ float bf2f(unsigned short h) {
    unsigned int u = ((unsigned int)h) << 16;
    return __builtin_bit_cast(float, u);
}
__device__ __forceinline__ void gld16(const void* g, void* l) {
    __builtin_amdgcn_global_load_lds(
        (const __attribute__((address_space(1))) void*)g,
        (__attribute__((address_space(3))) void*)l, 16, 0, 0);
}

// ============ kernel 0: weight prep ============
// Conv + fusion weights -> wB2, 80 half-chunks of 4 KB; full chunk cid = 8 KB:
//   cid = (L*3+k)*4+cq for conv (0..35), 36+cq for fusion.
//   half (nh) layout [g 0..3][c 0..63][e 0..7] bf16: W[co=nh*64+c][ci=cq*32+g*8+e].
//   RESIDUAL TRICK: identity added to tap k=2 (off=0) of every conv layer,
//   so conv(x)+x is a single GEMM (epilogue never re-reads x).
// wih  -> wihP[dd][r]  (packed bf16 pairs), whh/fusB -> wgruP[dd][r].
__global__ __launch_bounds__(256) void prep_kernel(
    const float* __restrict__ w0, const float* __restrict__ w1,
    const float* __restrict__ w2, const float* __restrict__ fus_w,
    const float* __restrict__ wih, const float* __restrict__ whh,
    unsigned short* __restrict__ wB2,
    unsigned int* __restrict__ wihP, unsigned int* __restrict__ wgruP)
{
    int idx = blockIdx.x * 256 + threadIdx.x;
    if (idx < 163840) {
        int cid2  = idx >> 11;           // 0..79
        int inner = idx & 2047;
        int g = inner >> 9;
        int c = (inner >> 3) & 63;
        int e = inner & 7;
        int nh   = cid2 & 1;
        int rest = cid2 >> 1;            // 0..39
        int cq   = rest & 3;
        int m    = rest >> 2;            // 0..8 conv, 9 fusion
        int ci = cq * 32 + g * 8 + e;
        int co = nh * 64 + c;
        float v;
        if (m < 9) {
            int L = m / 3, k = m % 3;
            const float* w = (L == 0) ? w0 : ((L == 1) ? w1 : w2);
            v = w[(co * 128 + ci) * 3 + k];
            if (k == 2 && ci == co) v += 1.0f;   // fold residual into GEMM
        } else {
            v = fus_w[co * 256 + ci];    // tc half of fus_w
        }
        wB2[idx] = f2bf(v);
    } else if (idx < 163840 + 24576) {
        int f  = idx - 163840;
        int dd = f / 384;
        int r  = f % 384;
        unsigned int lo = f2bf(wih[r * 128 + 2 * dd]);
        unsigned int hi = f2bf(wih[r * 128 + 2 * dd + 1]);
        wihP[f] = (hi << 16) | lo;
    } else if (idx < 163840 + 24576 + 32768) {
        int f  = idx - 163840 - 24576;
        int dd = f >> 9;
        int r  = f & 511;
        float v0, v1;
        if (r < 384) { v0 = whh[r * 128 + 2 * dd]; v1 = whh[r * 128 + 2 * dd + 1]; }
        else { const float* fw = fus_w + (r - 384) * 256 + 128;
               v0 = fw[2 * dd]; v1 = fw[2 * dd + 1]; }
        wgruP[f] = ((unsigned int)f2bf(v1) << 16) | (unsigned int)f2bf(v0);
    }
}

// ============ kernel 1: lengths, per-s max, u_type ============
__global__ __launch_bounds__(256) void len_kernel(
    const int* __restrict__ item_id, const int* __restrict__ u_type,
    int* __restrict__ lengths, int* __restrict__ maxlen,
    float* __restrict__ u_out)
{
    int s = blockIdx.x;
    int b = threadIdx.x;
    const int* row = item_id + (b * SS + s) * II;
    int cnt = 0;
    for (int i = 0; i < II; ++i) cnt += (row[i] > 0);
    lengths[b * SS + s] = cnt;
    __shared__ int red[256];
    red[b] = cnt;
    __syncthreads();
    for (int off = 128; off > 0; off >>= 1) {
        if (b < off) red[b] = max(red[b], red[b + off]);
        __syncthreads();
    }
    if (b == 0) maxlen[s] = red[0];
    if (s == 0) u_out[b] = (float)u_type[b];
}

// ============ kernel 2: masks + mean_emb ============
__global__ __launch_bounds__(128) void mean_kernel(
    const int* __restrict__ item_id, const int* __restrict__ eval_from,
    const float* __restrict__ emb,
    const int* __restrict__ lengths, const int* __restrict__ maxlen,
    float* __restrict__ mean_emb, float* __restrict__ mask_out)
{
    int bid = blockIdx.x;
    int b = bid >> 4, s = bid & 15;
    int tid = threadIdx.x;
    __shared__ int seqs[TT];
    __shared__ int msk[TT];
    int ml  = maxlen[s];
    int len = lengths[bid];
    int ef  = eval_from[b];
    if (tid < TT) {
        int v;
        if (tid == 0) v = BOS_ID;
        else { int it = item_id[bid * II + tid - 1]; v = it > 0 ? it : 0; }
        if (tid > ml) v = 0;
        int m = (v != 0) && !(tid == len && len > 0);
        seqs[tid] = v;
        msk[tid]  = m;
        mask_out[bid * TT + tid] = (m && (s >= ef)) ? 1.0f : 0.0f;
    }
    __syncthreads();
    int cnt = 0;
    for (int p = 0; p < TT; ++p) cnt += msk[p];
    float acc = 0.0f;
    int d = tid;
    for (int p = 0; p < TT; ++p) {
        if (msk[p]) acc += emb[seqs[p] * DD + d];
    }
    mean_emb[bid * DD + d] = acc / (float)max(cnt, 1);
}

// ============ kernel 3a: gi = me @ wih^T + bih ============
__global__ __launch_bounds__(384, 1) void gi_kernel(
    const float* __restrict__ me_all, const unsigned int* __restrict__ wihP,
    const float* __restrict__ bih, float* __restrict__ gi_all)
{
    __shared__ __align__(16) unsigned int wl[64 * 384];   // 96 KB
    __shared__ __align__(16) float me[DD];
    int t   = threadIdx.x;
    int blk = blockIdx.x;
    {
        const unsigned char* g = (const unsigned char*)wihP + t * 16;
        unsigned char* l = (unsigned char*)wl + t * 16;
#pragma unroll
        for (int i = 0; i < 16; ++i) gld16(g + i * 6144, l + i * 6144);
    }
    float bi = bih[t];
    asm volatile("s_waitcnt vmcnt(0)" ::: "memory");
    __syncthreads();
    for (int q = 0; q < 16; ++q) {
        int bs = blk * 16 + q;
        if (t < DD) me[t] = me_all[bs * DD + t];
        __syncthreads();
        float acc = bi;
#pragma unroll
        for (int dd = 0; dd < 64; ++dd) {
            unsigned int u = wl[dd * 384 + t];
            float f0 = __builtin_bit_cast(float, u << 16);
            float f1 = __builtin_bit_cast(float, u & 0xffff0000u);
            acc += f0 * me[2 * dd] + f1 * me[2 * dd + 1];
        }
        gi_all[bs * 384 + t] = acc;
        __syncthreads();
    }
}

// ============ kernel 3b: sequential GRU (gh, hb) ============
__global__ __launch_bounds__(512, 1) void gru_kernel(
    const unsigned int* __restrict__ wgruP, const float* __restrict__ bhh,
    const float* __restrict__ fus_b, const float* __restrict__ gi_all,
    float* __restrict__ hB)
{
    __shared__ __align__(16) unsigned int wl[64 * 512];   // 128 KB
    __shared__ float h[DD];
    __shared__ float g_z[DD], g_inn[DD], g_hn[DD];
    int t = threadIdx.x;
    int b = blockIdx.x;
    int j = t & 127;
    int grp = t >> 7;      // 0=r, 1=z, 2=n, 3=hb
    {
        const unsigned char* g = (const unsigned char*)wgruP + t * 16;
        unsigned char* l = (unsigned char*)wl + t * 16;
#pragma unroll
        for (int i = 0; i < 16; ++i) gld16(g + i * 8192, l + i * 8192);
    }
    float bias = (t < 384) ? bhh[t] : fus_b[j];
    if (t < DD) h[t] = 0.0f;
    asm volatile("s_waitcnt vmcnt(0)" ::: "memory");
    __syncthreads();
    for (int s = 0; s < SS; ++s) {
        float gi = (grp < 3) ? gi_all[(b * SS + s) * 384 + t] : 0.0f;
        float acc = bias;
#pragma unroll
        for (int dd = 0; dd < 64; ++dd) {
            unsigned int u = wl[dd * 512 + t];
            float f0 = __builtin_bit_cast(float, u << 16);
            float f1 = __builtin_bit_cast(float, u & 0xffff0000u);
            acc += f0 * h[2 * dd] + f1 * h[2 * dd + 1];
        }
        if (grp == 3) {
            hB[(s * BB + b) * DD + j] = acc;          // h BEFORE update; fus_b included
        } else if (grp == 1) { g_z[j] = gi + acc; }
        else if (grp == 2)   { g_inn[j] = gi; g_hn[j] = acc; }
        __syncthreads();
        if (grp == 0) {
            float r = 1.0f / (1.0f + expf(-(gi + acc)));
            float z = 1.0f / (1.0f + expf(-g_z[j]));
            float n = tanhf(g_inn[j] + r * g_hn[j]);
            h[j] = (1.0f - z) * n + z * h[j];
        }
        __syncthreads();
    }
}

// ============ kernel 4: MFMA TCN + fusion (v7) ============
// 128 threads = 2 waves; wave wv owns tile (bid*2+wv) entirely: 5 M-tiles x
// 8 N-tiles of 16x16, acc[5][8]. x in swizzled 256B rows (byte^=(row&7)<<4).
// 8 KB weight chunks co-staged into shared ring-2, one __syncthreads per
// chunk (its implicit vmcnt drain IS the stage wait). Residual folded into
// tap-2 weights. LDS = 53,760 B -> 3 blocks/CU (6 waves/CU).
__global__ __launch_bounds__(128) void tcn_kernel(
    const int* __restrict__ item_id, const float* __restrict__ emb,
    const int* __restrict__ maxlen,
    const unsigned short* __restrict__ wB2,
    const float* __restrict__ cb0, const float* __restrict__ cb1,
    const float* __restrict__ cb2,
    const float* __restrict__ hB, float* __restrict__ reps)
{
    __shared__ __align__(16) unsigned char lds_x[2][XT];   // 37376 B
    __shared__ __align__(16) unsigned char ring[2][8192];  // 16384 B

    const int tid = threadIdx.x, bid = blockIdx.x;
    const int lane = tid & 63, wv = tid >> 6;
    const int l15 = lane & 15, q4 = lane >> 4;
    const int tile = bid * 2 + wv;
    const int b = tile >> 4, s = tile & 15;
    const int ml = maxlen[s];

    const unsigned char* wbase = (const unsigned char*)wB2 + wv * 4096 + lane * 16;
    unsigned char* xb = lds_x[wv];

    // stage chunk 0 -> ring slot 0 (each wave stages its 4 KB half)
#pragma unroll
    for (int i = 0; i < 4; ++i)
        gld16(wbase + i * 1024, &ring[0][wv * 4096 + i * 1024]);

    // per-lane seq value (p = lane), broadcast later via readlane
    int seqv;
    {
        int p = lane, v;
        if (p == 0) v = BOS_ID;
        else { int it = item_id[tile * II + p - 1]; v = it > 0 ? it : 0; }
        if (p > ml) v = 0;
        seqv = v;
    }
    int seq64;
    { int it = item_id[tile * II + 63]; seq64 = (64 > ml) ? 0 : (it > 0 ? it : 0); }

    // zero guard rows 0..7 of OWN tile (2048 B, wave-local: no barrier needed)
    { float4 z = {0.f, 0.f, 0.f, 0.f};
      *(float4*)(xb + lane * 16) = z;
      *(float4*)(xb + 1024 + lane * 16) = z; }

    // gather embeddings -> rows 8..72, bf16 pairs, swizzled
#pragma unroll 4
    for (int p = 0; p < TT; ++p) {
        int sp = (p < 64) ? __builtin_amdgcn_readlane(seqv, p) : seq64;
        const float2 e = *((const float2*)(emb + (long)sp * DD) + lane);
        unsigned int pk = ((unsigned int)f2bf(e.y) << 16) | (unsigned int)f2bf(e.x);
        *(unsigned int*)(xb + (8 + p) * XROW + ((lane * 4) ^ ((p & 7) << 4))) = pk;
    }

    // preload biases + h-part of fusion (no global loads in the main loop)
    float bias0[8], bias1[8], bias2[8], hb[8];
#pragma unroll
    for (int nt = 0; nt < 8; ++nt) {
        int co = nt * 16 + l15;
        bias0[nt] = cb0[co]; bias1[nt] = cb1[co]; bias2[nt] = cb2[co];
        hb[nt] = hB[(s * BB + b) * DD + co];
    }

    f32x4 acc[5][8];

#pragma unroll 1
    for (int cid = 0; cid < 40; ++cid) {
        int L = 0, kq = 0, cq, off;
        if (cid < 36) { L = cid / 12; kq = cid - L * 12; int k = kq >> 2; cq = kq & 3; off = (2 - k) << L; }
        else { cq = cid - 36; off = 0; }
        if (cid == 36 || (cid < 36 && kq == 0)) {   // zero acc at layer/fusion start
#pragma unroll
            for (int mt = 0; mt < 5; ++mt)
#pragma unroll
                for (int nt = 0; nt < 8; ++nt)
#pragma unroll
                    for (int r = 0; r < 4; ++r) acc[mt][nt][r] = 0.0f;
        }
        // __syncthreads drains vmcnt+lgkmcnt: stage(cid) landed (both waves),
        // and slot (cid+1)&1 is no longer being read by the other wave.
        __syncthreads();

        if (cid <= 38) {   // stage chunk cid+1 into the other slot
            const unsigned char* src = wbase + (size_t)(cid + 1) * 8192;
            unsigned char* dst = &ring[(cid + 1) & 1][wv * 4096];
#pragma unroll
            for (int i = 0; i < 4; ++i) gld16(src + i * 1024, dst + i * 1024);
        }

        const unsigned char* sb = &ring[cid & 1][0];
        short8 af[5];
#pragma unroll
        for (int mt = 0; mt < 5; ++mt) {
            int rowA = 8 + mt * 16 + l15 - off;
            af[mt] = *(const short8*)(xb + rowA * XROW +
                                      ((cq * 64 + q4 * 16) ^ ((rowA & 7) << 4)));
        }
        __builtin_amdgcn_s_setprio(1);
#pragma unroll
        for (int nt = 0; nt < 8; ++nt) {
            short8 bf = *(const short8*)(sb + (nt >> 2) * 4096 + q4 * 1024 +
                                         ((nt & 3) * 16 + l15) * 16);
#pragma unroll
            for (int mt = 0; mt < 5; ++mt)
                acc[mt][nt] = __builtin_amdgcn_mfma_f32_16x16x32_bf16(
                    af[mt], bf, acc[mt][nt], 0, 0, 0);
        }
        __builtin_amdgcn_s_setprio(0);

        if (cid < 36 && kq == 11) {   // layer epilogue: relu(acc+bias) -> x, write-only
#pragma unroll
            for (int nt = 0; nt < 8; ++nt) {
                float bia = (L == 0) ? bias0[nt] : ((L == 1) ? bias1[nt] : bias2[nt]);
                int cb2b = (nt * 16 + l15) * 2;
#pragma unroll
                for (int mt = 0; mt < 5; ++mt)
#pragma unroll
                    for (int r = 0; r < 4; ++r) {
                        int p = mt * 16 + q4 * 4 + r;
                        if (p < TT) {
                            int row = 8 + p;
                            float v = acc[mt][nt][r] + bia;
                            *(unsigned short*)(xb + row * XROW +
                                               (cb2b ^ ((row & 7) << 4))) =
                                f2bf(v > 0.f ? v : 0.f);
                        }
                    }
            }
            // own-wave RAW: writes must land before next layer's ds_reads
            asm volatile("s_waitcnt lgkmcnt(0)" ::: "memory");
            __builtin_amdgcn_sched_barrier(0);
        }
    }

    // fusion writeout: reps[p][j] = (p<=ml) ? acc + hb : 0
    long ob = (long)tile * (TT * DD);
#pragma unroll
    for (int mt = 0; mt < 5; ++mt)
#pragma unroll
        for (int nt = 0; nt < 8; ++nt)
#pragma unroll
            for (int r = 0; r < 4; ++r) {
                int p = mt * 16 + q4 * 4 + r;
                if (p < TT) {
                    float v = (p <= ml) ? (acc[mt][nt][r] + hb[nt]) : 0.0f;
                    reps[ob + p * DD + nt * 16 + l15] = v;
                }
            }
}

extern "C" void kernel_launch(void* const* d_in, const int* in_sizes, int n_in,
                              void* d_out, int out_size, void* d_ws, size_t ws_size,
                              hipStream_t stream) {
    const int*   item_id   = (const int*)  d_in[0];
    const int*   eval_from = (const int*)  d_in[1];
    const int*   u_type    = (const int*)  d_in[2];
    const float* emb       = (const float*)d_in[3];
    const float* conv_w0   = (const float*)d_in[4];
    const float* conv_b0   = (const float*)d_in[5];
    const float* conv_w1   = (const float*)d_in[6];
    const float* conv_b1   = (const float*)d_in[7];
    const float* conv_w2   = (const float*)d_in[8];
    const float* conv_b2   = (const float*)d_in[9];
    const float* gru_wih   = (const float*)d_in[10];
    const float* gru_whh   = (const float*)d_in[11];
    const float* gru_bih   = (const float*)d_in[12];
    const float* gru_bhh   = (const float*)d_in[13];
    const float* fus_w     = (const float*)d_in[14];
    const float* fus_b     = (const float*)d_in[15];

    char* ws = (char*)d_ws;
    int*            lengths  = (int*)           (ws + OFF_LEN);
    int*            maxlen   = (int*)           (ws + OFF_ML);
    float*          mean_emb = (float*)         (ws + OFF_ME);
    float*          hB       = (float*)         (ws + OFF_HB);
    unsigned short* wB2      = (unsigned short*)(ws + OFF_WB2);
    unsigned int*   wihP     = (unsigned int*)  (ws + OFF_WIHP);
    unsigned int*   wgruP    = (unsigned int*)  (ws + OFF_WGRU);
    float*          gi_all   = (float*)         (ws + OFF_GI);

    float* out  = (float*)d_out;
    float* reps = out;
    float* mout = out + OUT_MASK;
    float* uout = out + OUT_UTYPE;

    prep_kernel<<<864, 256, 0, stream>>>(conv_w0, conv_w1, conv_w2, fus_w,
                                         gru_wih, gru_whh, wB2, wihP, wgruP);
    len_kernel<<<SS, 256, 0, stream>>>(item_id, u_type, lengths, maxlen, uout);
    mean_kernel<<<BB * SS, 128, 0, stream>>>(item_id, eval_from, emb, lengths, maxlen,
                                             mean_emb, mout);
    gi_kernel<<<BB, 384, 0, stream>>>(mean_emb, wihP, gru_bih, gi_all);
    gru_kernel<<<BB, 512, 0, stream>>>(wgruP, gru_bhh, fus_b, gi_all, hB);
    tcn_kernel<<<BB * SS / 2, 128, 0, stream>>>(item_id, emb, maxlen, wB2,
                                                conv_b0, conv_b1, conv_b2, hB, reps);
}

// Round 8
// 338.314 us; speedup vs baseline: 1.3348x; 1.3102x over previous
//
#include <hip/hip_runtime.h>

#define BB 256
#define SS 16
#define II 64
#define DD 128
#define TT 65            // I + 1 (BOS prepended)
#define BOS_ID 100000
#define XROW 256         // x row stride: 128 bf16, XOR-16B swizzled
#define XROWS 73         // 8 zero guard rows + 65 positions
#define XT (XROWS*XROW)  // 18688 B per tile

// ---------------- ws layout (bytes) ----------------
#define OFF_LEN  0                        // int lengths[B][S]            16384
#define OFF_ML   16384                    // int maxlen[S]                64
#define OFF_ME   32768                    // float mean_emb[B][S][D]      2 MB
#define OFF_HB   (32768 + 2097152)        // float hB[S][B][D]            2 MB
#define OFF_WB2  (OFF_HB + 2097152)       // bf16 wB2[80 half-chunks][2048]  327680
#define OFF_WIHP (OFF_WB2 + 327680)       // u32 wihP[64][384]            98304
#define OFF_WGRU (OFF_WIHP + 98304)       // u32 wgruP[64][512]           131072
#define OFF_GI   (OFF_WGRU + 131072)      // float gi[4096][384]          6291456

// ---------------- out layout (float elements) ----------------
#define OUT_MASK  (BB*SS*TT*DD)          // 34,078,720
#define OUT_UTYPE (OUT_MASK + BB*SS*TT)

typedef __attribute__((ext_vector_type(8))) short short8;
typedef __attribute__((ext_vector_type(4))) float f32x4;

__device__ __forceinline__ unsigned short f2bf(float f) {
    unsigned int u = __builtin_bit_cast(unsigned int, f);
    return (unsigned short)((u + 0x7fffu + ((u >> 16) & 1u)) >> 16);  // RNE
}
__device__ __forceinline__ void gld16(const void* g, void* l) {
    __builtin_amdgcn_global_load_lds(
        (const __attribute__((address_space(1))) void*)g,
        (__attribute__((address_space(3))) void*)l, 16, 0, 0);
}

// ============ kernel 0: weight prep ============
// Conv + fusion weights -> wB2, 80 half-chunks of 4 KB; full chunk cid = 8 KB:
//   cid = (L*3+k)*4+cq for conv (0..35), 36+cq for fusion.
//   half (nh) layout [g 0..3][c 0..63][e 0..7] bf16: W[co=nh*64+c][ci=cq*32+g*8+e].
//   RESIDUAL TRICK: identity added to tap k=2 (off=0) of every conv layer.
__global__ __launch_bounds__(256) void prep_kernel(
    const float* __restrict__ w0, const float* __restrict__ w1,
    const float* __restrict__ w2, const float* __restrict__ fus_w,
    const float* __restrict__ wih, const float* __restrict__ whh,
    unsigned short* __restrict__ wB2,
    unsigned int* __restrict__ wihP, unsigned int* __restrict__ wgruP)
{
    int idx = blockIdx.x * 256 + threadIdx.x;
    if (idx < 163840) {
        int cid2  = idx >> 11;           // 0..79
        int inner = idx & 2047;
        int g = inner >> 9;
        int c = (inner >> 3) & 63;
        int e = inner & 7;
        int nh   = cid2 & 1;
        int rest = cid2 >> 1;            // 0..39
        int cq   = rest & 3;
        int m    = rest >> 2;            // 0..8 conv, 9 fusion
        int ci = cq * 32 + g * 8 + e;
        int co = nh * 64 + c;
        float v;
        if (m < 9) {
            int L = m / 3, k = m % 3;
            const float* w = (L == 0) ? w0 : ((L == 1) ? w1 : w2);
            v = w[(co * 128 + ci) * 3 + k];
            if (k == 2 && ci == co) v += 1.0f;   // fold residual into GEMM
        } else {
            v = fus_w[co * 256 + ci];    // tc half of fus_w
        }
        wB2[idx] = f2bf(v);
    } else if (idx < 163840 + 24576) {
        int f  = idx - 163840;
        int dd = f / 384;
        int r  = f % 384;
        unsigned int lo = f2bf(wih[r * 128 + 2 * dd]);
        unsigned int hi = f2bf(wih[r * 128 + 2 * dd + 1]);
        wihP[f] = (hi << 16) | lo;
    } else if (idx < 163840 + 24576 + 32768) {
        int f  = idx - 163840 - 24576;
        int dd = f >> 9;
        int r  = f & 511;
        float v0, v1;
        if (r < 384) { v0 = whh[r * 128 + 2 * dd]; v1 = whh[r * 128 + 2 * dd + 1]; }
        else { const float* fw = fus_w + (r - 384) * 256 + 128;
               v0 = fw[2 * dd]; v1 = fw[2 * dd + 1]; }
        wgruP[f] = ((unsigned int)f2bf(v1) << 16) | (unsigned int)f2bf(v0);
    }
}

// ============ kernel 1: lengths, per-s max, u_type ============
__global__ __launch_bounds__(256) void len_kernel(
    const int* __restrict__ item_id, const int* __restrict__ u_type,
    int* __restrict__ lengths, int* __restrict__ maxlen,
    float* __restrict__ u_out)
{
    int s = blockIdx.x;
    int b = threadIdx.x;
    const int* row = item_id + (b * SS + s) * II;
    int cnt = 0;
    for (int i = 0; i < II; ++i) cnt += (row[i] > 0);
    lengths[b * SS + s] = cnt;
    __shared__ int red[256];
    red[b] = cnt;
    __syncthreads();
    for (int off = 128; off > 0; off >>= 1) {
        if (b < off) red[b] = max(red[b], red[b + off]);
        __syncthreads();
    }
    if (b == 0) maxlen[s] = red[0];
    if (s == 0) u_out[b] = (float)u_type[b];
}

// ============ kernel 2: masks + mean_emb ============
__global__ __launch_bounds__(128) void mean_kernel(
    const int* __restrict__ item_id, const int* __restrict__ eval_from,
    const float* __restrict__ emb,
    const int* __restrict__ lengths, const int* __restrict__ maxlen,
    float* __restrict__ mean_emb, float* __restrict__ mask_out)
{
    int bid = blockIdx.x;
    int b = bid >> 4, s = bid & 15;
    int tid = threadIdx.x;
    __shared__ int seqs[TT];
    __shared__ int msk[TT];
    int ml  = maxlen[s];
    int len = lengths[bid];
    int ef  = eval_from[b];
    if (tid < TT) {
        int v;
        if (tid == 0) v = BOS_ID;
        else { int it = item_id[bid * II + tid - 1]; v = it > 0 ? it : 0; }
        if (tid > ml) v = 0;
        int m = (v != 0) && !(tid == len && len > 0);
        seqs[tid] = v;
        msk[tid]  = m;
        mask_out[bid * TT + tid] = (m && (s >= ef)) ? 1.0f : 0.0f;
    }
    __syncthreads();
    int cnt = 0;
    for (int p = 0; p < TT; ++p) cnt += msk[p];
    float acc = 0.0f;
    int d = tid;
    for (int p = 0; p < TT; ++p) {
        if (msk[p]) acc += emb[seqs[p] * DD + d];
    }
    mean_emb[bid * DD + d] = acc / (float)max(cnt, 1);
}

// ============ kernel 3a: gi = me @ wih^T + bih ============
__global__ __launch_bounds__(384, 1) void gi_kernel(
    const float* __restrict__ me_all, const unsigned int* __restrict__ wihP,
    const float* __restrict__ bih, float* __restrict__ gi_all)
{
    __shared__ __align__(16) unsigned int wl[64 * 384];   // 96 KB
    __shared__ __align__(16) float me[DD];
    int t   = threadIdx.x;
    int blk = blockIdx.x;
    {
        const unsigned char* g = (const unsigned char*)wihP + t * 16;
        unsigned char* l = (unsigned char*)wl + t * 16;
#pragma unroll
        for (int i = 0; i < 16; ++i) gld16(g + i * 6144, l + i * 6144);
    }
    float bi = bih[t];
    asm volatile("s_waitcnt vmcnt(0)" ::: "memory");
    __syncthreads();
    for (int q = 0; q < 16; ++q) {
        int bs = blk * 16 + q;
        if (t < DD) me[t] = me_all[bs * DD + t];
        __syncthreads();
        float acc = bi;
#pragma unroll
        for (int dd = 0; dd < 64; ++dd) {
            unsigned int u = wl[dd * 384 + t];
            float f0 = __builtin_bit_cast(float, u << 16);
            float f1 = __builtin_bit_cast(float, u & 0xffff0000u);
            acc += f0 * me[2 * dd] + f1 * me[2 * dd + 1];
        }
        gi_all[bs * 384 + t] = acc;
        __syncthreads();
    }
}

// ============ kernel 3b: sequential GRU (gh, hb) ============
__global__ __launch_bounds__(512, 1) void gru_kernel(
    const unsigned int* __restrict__ wgruP, const float* __restrict__ bhh,
    const float* __restrict__ fus_b, const float* __restrict__ gi_all,
    float* __restrict__ hB)
{
    __shared__ __align__(16) unsigned int wl[64 * 512];   // 128 KB
    __shared__ float h[DD];
    __shared__ float g_z[DD], g_inn[DD], g_hn[DD];
    int t = threadIdx.x;
    int b = blockIdx.x;
    int j = t & 127;
    int grp = t >> 7;      // 0=r, 1=z, 2=n, 3=hb
    {
        const unsigned char* g = (const unsigned char*)wgruP + t * 16;
        unsigned char* l = (unsigned char*)wl + t * 16;
#pragma unroll
        for (int i = 0; i < 16; ++i) gld16(g + i * 8192, l + i * 8192);
    }
    float bias = (t < 384) ? bhh[t] : fus_b[j];
    if (t < DD) h[t] = 0.0f;
    asm volatile("s_waitcnt vmcnt(0)" ::: "memory");
    __syncthreads();
    for (int s = 0; s < SS; ++s) {
        float gi = (grp < 3) ? gi_all[(b * SS + s) * 384 + t] : 0.0f;
        float acc = bias;
#pragma unroll
        for (int dd = 0; dd < 64; ++dd) {
            unsigned int u = wl[dd * 512 + t];
            float f0 = __builtin_bit_cast(float, u << 16);
            float f1 = __builtin_bit_cast(float, u & 0xffff0000u);
            acc += f0 * h[2 * dd] + f1 * h[2 * dd + 1];
        }
        if (grp == 3) {
            hB[(s * BB + b) * DD + j] = acc;          // h BEFORE update; fus_b included
        } else if (grp == 1) { g_z[j] = gi + acc; }
        else if (grp == 2)   { g_inn[j] = gi; g_hn[j] = acc; }
        __syncthreads();
        if (grp == 0) {
            float r = 1.0f / (1.0f + expf(-(gi + acc)));
            float z = 1.0f / (1.0f + expf(-g_z[j]));
            float n = tanhf(g_inn[j] + r * g_hn[j]);
            h[j] = (1.0f - z) * n + z * h[j];
        }
        __syncthreads();
    }
}

// ============ kernel 4: MFMA TCN + fusion (v8 = round-4 skeleton + swaps) ============
// 256 threads = 4 waves; wave = (tile t, co-half nh). acc[5][4] (80 VGPR).
// Conv layers: mfma(W, x) -> D[co][p]  (epilogue: cvt_pk pairs along co, b64 writes)
// Fusion:      mfma(x, W) -> D[p][co]  (coalesced global writeout)
// Per-wave private ring-2 of 4 KB half-chunks, counted vmcnt(4), no barriers
// in the chunk loop except the 3 layer epilogues. Residual folded into tap-2.
__global__ __launch_bounds__(256) void tcn_kernel(
    const int* __restrict__ item_id, const float* __restrict__ emb,
    const int* __restrict__ maxlen,
    const unsigned short* __restrict__ wB2,
    const float* __restrict__ cb0, const float* __restrict__ cb1,
    const float* __restrict__ cb2,
    const float* __restrict__ hB, float* __restrict__ reps)
{
    __shared__ __align__(16) unsigned char lds_x[2][XT];      // 37376 B
    __shared__ __align__(16) unsigned char ring[4][2][4096];  // 32768 B

    const int tid = threadIdx.x, bid = blockIdx.x;
    const int lane = tid & 63, wv = tid >> 6;
    const int l15 = lane & 15, q4 = lane >> 4;
    const int t = wv >> 1, nh = wv & 1;
    const int tile = bid * 2 + t;
    const int b = tile >> 4, s = tile & 15;
    const int ml = maxlen[s];

    const unsigned char* wbase = (const unsigned char*)wB2 + nh * 4096 + lane * 16;
    unsigned char* xb = lds_x[t];

    // prologue: stage chunks 0,1 into ring slots 0,1 (per-wave private halves)
#pragma unroll
    for (int i = 0; i < 4; ++i) gld16(wbase + i * 1024, &ring[wv][0][i * 1024]);
#pragma unroll
    for (int i = 0; i < 4; ++i) gld16(wbase + 8192 + i * 1024, &ring[wv][1][i * 1024]);

    // per-lane seq value (p = lane), broadcast via readlane
    int seqv;
    {
        int p = lane, v;
        if (p == 0) v = BOS_ID;
        else { int it = item_id[tile * II + p - 1]; v = it > 0 ? it : 0; }
        if (p > ml) v = 0;
        seqv = v;
    }
    int seq64;
    { int it = item_id[tile * II + 63]; seq64 = (64 > ml) ? 0 : (it > 0 ? it : 0); }

    // zero guard rows 0..7 of own tile (each wave half: 1024 B)
    { float4 z = {0.f, 0.f, 0.f, 0.f};
      *(float4*)(xb + nh * 1024 + lane * 16) = z; }

    // gather embeddings -> rows 8..72, bf16 pairs, swizzled; waves split rows
    for (int p = nh; p < TT; p += 2) {
        int sp = (p < 64) ? __builtin_amdgcn_readlane(seqv, p) : seq64;
        const float2 e = *((const float2*)(emb + (long)sp * DD) + lane);
        unsigned int pk;
        asm("v_cvt_pk_bf16_f32 %0, %1, %2" : "=v"(pk) : "v"(e.x), "v"(e.y));
        *(unsigned int*)(xb + (8 + p) * XROW + ((lane * 4) ^ ((p & 7) << 4))) = pk;
    }
    __syncthreads();   // both halves of x visible to both tile-waves

    f32x4 acc[5][4];

#pragma unroll 1
    for (int cid = 0; cid < 40; ++cid) {
        int L = 0, kq = 0, cq, off;
        if (cid < 36) { L = cid / 12; kq = cid - L * 12; int k = kq >> 2; cq = kq & 3; off = (2 - k) << L; }
        else { cq = cid - 36; off = 0; }
        if (cid == 36 || (cid < 36 && kq == 0)) {   // zero acc at layer/fusion start
#pragma unroll
            for (int pt = 0; pt < 5; ++pt)
#pragma unroll
                for (int ct = 0; ct < 4; ++ct)
#pragma unroll
                    for (int r = 0; r < 4; ++r) acc[pt][ct][r] = 0.0f;
        }
        // counted wait: one newer chunk (4 loads) may stay in flight
        if (cid < 39) asm volatile("s_waitcnt vmcnt(4)" ::: "memory");
        else          asm volatile("s_waitcnt vmcnt(0)" ::: "memory");

        const unsigned char* sb = &ring[wv][cid & 1][0];
        short8 wf[4], xf[5];
#pragma unroll
        for (int ct = 0; ct < 4; ++ct)
            wf[ct] = *(const short8*)(sb + q4 * 1024 + (ct * 16 + l15) * 16);
#pragma unroll
        for (int pt = 0; pt < 5; ++pt) {
            int rowA = 8 + pt * 16 + l15 - off;
            xf[pt] = *(const short8*)(xb + rowA * XROW +
                                      ((cq * 64 + q4 * 16) ^ ((rowA & 7) << 4)));
        }
        // frag reads landed before overwriting this ring slot with chunk cid+2
        asm volatile("s_waitcnt lgkmcnt(0)" ::: "memory");
        __builtin_amdgcn_sched_barrier(0);
        if (cid <= 37) {
            const unsigned char* src = wbase + (size_t)(cid + 2) * 8192;
#pragma unroll
            for (int i = 0; i < 4; ++i)
                gld16(src + i * 1024, &ring[wv][cid & 1][i * 1024]);
        }

        __builtin_amdgcn_s_setprio(1);
        if (cid < 36) {   // conv: D[co][p] = W · x
#pragma unroll
            for (int ct = 0; ct < 4; ++ct)
#pragma unroll
                for (int pt = 0; pt < 5; ++pt)
                    acc[pt][ct] = __builtin_amdgcn_mfma_f32_16x16x32_bf16(
                        wf[ct], xf[pt], acc[pt][ct], 0, 0, 0);
        } else {          // fusion: D[p][co] = x · W
#pragma unroll
            for (int nt = 0; nt < 4; ++nt)
#pragma unroll
                for (int pt = 0; pt < 5; ++pt)
                    acc[pt][nt] = __builtin_amdgcn_mfma_f32_16x16x32_bf16(
                        xf[pt], wf[nt], acc[pt][nt], 0, 0, 0);
        }
        __builtin_amdgcn_s_setprio(0);

        if (cid < 36 && kq == 11) {   // layer epilogue: relu(acc+bias) -> x, packed b64
            const float* cb = (L == 0) ? cb0 : ((L == 1) ? cb1 : cb2);
            __syncthreads();          // all reads of current x done
#pragma unroll
            for (int ct = 0; ct < 4; ++ct) {
                f32x4 b4 = *(const f32x4*)(cb + nh * 64 + ct * 16 + q4 * 4);
#pragma unroll
                for (int pt = 0; pt < 5; ++pt) {
                    int p = pt * 16 + l15;
                    if (p < TT) {
                        float v0 = acc[pt][ct][0] + b4[0]; v0 = v0 > 0.f ? v0 : 0.f;
                        float v1 = acc[pt][ct][1] + b4[1]; v1 = v1 > 0.f ? v1 : 0.f;
                        float v2 = acc[pt][ct][2] + b4[2]; v2 = v2 > 0.f ? v2 : 0.f;
                        float v3 = acc[pt][ct][3] + b4[3]; v3 = v3 > 0.f ? v3 : 0.f;
                        unsigned int lo, hi;
                        asm("v_cvt_pk_bf16_f32 %0, %1, %2" : "=v"(lo) : "v"(v0), "v"(v1));
                        asm("v_cvt_pk_bf16_f32 %0, %1, %2" : "=v"(hi) : "v"(v2), "v"(v3));
                        int row = 8 + p;
                        uint2 w2; w2.x = lo; w2.y = hi;
                        *(uint2*)(xb + row * XROW +
                                  ((nh * 128 + ct * 32 + q4 * 8) ^ ((row & 7) << 4))) = w2;
                    }
                }
            }
            __syncthreads();          // writes visible before next layer's reads
        }
    }

    // fusion writeout: reps[p][co] = (p<=ml) ? acc + hb : 0   (coalesced)
    float hb[4];
#pragma unroll
    for (int nt = 0; nt < 4; ++nt)
        hb[nt] = hB[(s * BB + b) * DD + nh * 64 + nt * 16 + l15];
    long ob = (long)tile * (TT * DD);
#pragma unroll
    for (int mt = 0; mt < 5; ++mt)
#pragma unroll
        for (int nt = 0; nt < 4; ++nt)
#pragma unroll
            for (int r = 0; r < 4; ++r) {
                int p = mt * 16 + q4 * 4 + r;
                if (p < TT) {
                    float v = (p <= ml) ? (acc[mt][nt][r] + hb[nt]) : 0.0f;
                    reps[ob + p * DD + nh * 64 + nt * 16 + l15] = v;
                }
            }
}

extern "C" void kernel_launch(void* const* d_in, const int* in_sizes, int n_in,
                              void* d_out, int out_size, void* d_ws, size_t ws_size,
                              hipStream_t stream) {
    const int*   item_id   = (const int*)  d_in[0];
    const int*   eval_from = (const int*)  d_in[1];
    const int*   u_type    = (const int*)  d_in[2];
    const float* emb       = (const float*)d_in[3];
    const float* conv_w0   = (const float*)d_in[4];
    const float* conv_b0   = (const float*)d_in[5];
    const float* conv_w1   = (const float*)d_in[6];
    const float* conv_b1   = (const float*)d_in[7];
    const float* conv_w2   = (const float*)d_in[8];
    const float* conv_b2   = (const float*)d_in[9];
    const float* gru_wih   = (const float*)d_in[10];
    const float* gru_whh   = (const float*)d_in[11];
    const float* gru_bih   = (const float*)d_in[12];
    const float* gru_bhh   = (const float*)d_in[13];
    const float* fus_w     = (const float*)d_in[14];
    const float* fus_b     = (const float*)d_in[15];

    char* ws = (char*)d_ws;
    int*            lengths  = (int*)           (ws + OFF_LEN);
    int*            maxlen   = (int*)           (ws + OFF_ML);
    float*          mean_emb = (float*)         (ws + OFF_ME);
    float*          hB       = (float*)         (ws + OFF_HB);
    unsigned short* wB2      = (unsigned short*)(ws + OFF_WB2);
    unsigned int*   wihP     = (unsigned int*)  (ws + OFF_WIHP);
    unsigned int*   wgruP    = (unsigned int*)  (ws + OFF_WGRU);
    float*          gi_all   = (float*)         (ws + OFF_GI);

    float* out  = (float*)d_out;
    float* reps = out;
    float* mout = out + OUT_MASK;
    float* uout = out + OUT_UTYPE;

    prep_kernel<<<864, 256, 0, stream>>>(conv_w0, conv_w1, conv_w2, fus_w,
                                         gru_wih, gru_whh, wB2, wihP, wgruP);
    len_kernel<<<SS, 256, 0, stream>>>(item_id, u_type, lengths, maxlen, uout);
    mean_kernel<<<BB * SS, 128, 0, stream>>>(item_id, eval_from, emb, lengths, maxlen,
                                             mean_emb, mout);
    gi_kernel<<<BB, 384, 0, stream>>>(mean_emb, wihP, gru_bih, gi_all);
    gru_kernel<<<BB, 512, 0, stream>>>(wgruP, gru_bhh, fus_b, gi_all, hB);
    tcn_kernel<<<BB * SS / 2, 256, 0, stream>>>(item_id, emb, maxlen, wB2,
                                                conv_b0, conv_b1, conv_b2, hB, reps);
}

// Round 9
// 304.318 us; speedup vs baseline: 1.4839x; 1.1117x over previous
//
#include <hip/hip_runtime.h>

#define BB 256
#define SS 16
#define II 64
#define DD 128
#define TT 65            // I + 1 (BOS prepended)
#define BOS_ID 100000
#define XROW 304         // padded x row stride (256 B data + 48 B pad)
#define XROWS 73         // 8 zero guard rows + 65 positions
#define XT (XROWS*XROW)  // 22192 B per tile

// ---------------- ws layout (bytes) ----------------
#define OFF_LEN  0                        // int lengths[B][S]            16384
#define OFF_ML   16384                    // int maxlen[S]                64
#define OFF_ME   32768                    // float mean_emb[B][S][D]      2 MB
#define OFF_HB   (32768 + 2097152)        // float hB[S][B][D]            2 MB
#define OFF_WB2  (OFF_HB + 2097152)       // bf16 wB2[80 half-chunks][2048]  327680
#define OFF_WIHP (OFF_WB2 + 327680)       // u32 wihP[64][384]            98304
#define OFF_WGRU (OFF_WIHP + 98304)       // u32 wgruP[64][512]           131072
#define OFF_GI   (OFF_WGRU + 131072)      // float gi[4096][384]          6291456

// ---------------- out layout (float elements) ----------------
#define OUT_MASK  (BB*SS*TT*DD)          // 34,078,720
#define OUT_UTYPE (OUT_MASK + BB*SS*TT)

typedef __attribute__((ext_vector_type(8))) short short8;
typedef __attribute__((ext_vector_type(4))) float f32x4;

__device__ __forceinline__ unsigned short f2bf(float f) {
    unsigned int u = __builtin_bit_cast(unsigned int, f);
    return (unsigned short)((u + 0x7fffu + ((u >> 16) & 1u)) >> 16);  // RNE
}
__device__ __forceinline__ void gld16(const void* g, void* l) {
    __builtin_amdgcn_global_load_lds(
        (const __attribute__((address_space(1))) void*)g,
        (__attribute__((address_space(3))) void*)l, 16, 0, 0);
}

// ============ kernel 0: weight prep ============
// Conv + fusion weights -> wB2, 80 half-chunks of 4 KB; full chunk cid = 8 KB:
//   cid = (L*3+k)*4+cq for conv (0..35), 36+cq for fusion.
//   half (nh) layout [g 0..3][c 0..63][e 0..7] bf16: W[co=nh*64+c][ci=cq*32+g*8+e].
//   RESIDUAL TRICK: identity added to tap k=2 (off=0) of every conv layer,
//   so conv(x)+x is a single GEMM (epilogue never re-reads x).
__global__ __launch_bounds__(256) void prep_kernel(
    const float* __restrict__ w0, const float* __restrict__ w1,
    const float* __restrict__ w2, const float* __restrict__ fus_w,
    const float* __restrict__ wih, const float* __restrict__ whh,
    unsigned short* __restrict__ wB2,
    unsigned int* __restrict__ wihP, unsigned int* __restrict__ wgruP)
{
    int idx = blockIdx.x * 256 + threadIdx.x;
    if (idx < 163840) {
        int cid2  = idx >> 11;           // 0..79
        int inner = idx & 2047;
        int g = inner >> 9;
        int c = (inner >> 3) & 63;
        int e = inner & 7;
        int nh   = cid2 & 1;
        int rest = cid2 >> 1;            // 0..39
        int cq   = rest & 3;
        int m    = rest >> 2;            // 0..8 conv, 9 fusion
        int ci = cq * 32 + g * 8 + e;
        int co = nh * 64 + c;
        float v;
        if (m < 9) {
            int L = m / 3, k = m % 3;
            const float* w = (L == 0) ? w0 : ((L == 1) ? w1 : w2);
            v = w[(co * 128 + ci) * 3 + k];
            if (k == 2 && ci == co) v += 1.0f;   // fold residual into GEMM
        } else {
            v = fus_w[co * 256 + ci];    // tc half of fus_w
        }
        wB2[idx] = f2bf(v);
    } else if (idx < 163840 + 24576) {
        int f  = idx - 163840;
        int dd = f / 384;
        int r  = f % 384;
        unsigned int lo = f2bf(wih[r * 128 + 2 * dd]);
        unsigned int hi = f2bf(wih[r * 128 + 2 * dd + 1]);
        wihP[f] = (hi << 16) | lo;
    } else if (idx < 163840 + 24576 + 32768) {
        int f  = idx - 163840 - 24576;
        int dd = f >> 9;
        int r  = f & 511;
        float v0, v1;
        if (r < 384) { v0 = whh[r * 128 + 2 * dd]; v1 = whh[r * 128 + 2 * dd + 1]; }
        else { const float* fw = fus_w + (r - 384) * 256 + 128;
               v0 = fw[2 * dd]; v1 = fw[2 * dd + 1]; }
        wgruP[f] = ((unsigned int)f2bf(v1) << 16) | (unsigned int)f2bf(v0);
    }
}

// ============ kernel 1: lengths, per-s max, u_type ============
__global__ __launch_bounds__(256) void len_kernel(
    const int* __restrict__ item_id, const int* __restrict__ u_type,
    int* __restrict__ lengths, int* __restrict__ maxlen,
    float* __restrict__ u_out)
{
    int s = blockIdx.x;
    int b = threadIdx.x;
    const int* row = item_id + (b * SS + s) * II;
    int cnt = 0;
    for (int i = 0; i < II; ++i) cnt += (row[i] > 0);
    lengths[b * SS + s] = cnt;
    __shared__ int red[256];
    red[b] = cnt;
    __syncthreads();
    for (int off = 128; off > 0; off >>= 1) {
        if (b < off) red[b] = max(red[b], red[b + off]);
        __syncthreads();
    }
    if (b == 0) maxlen[s] = red[0];
    if (s == 0) u_out[b] = (float)u_type[b];
}

// ============ kernel 2: masks + mean_emb ============
__global__ __launch_bounds__(128) void mean_kernel(
    const int* __restrict__ item_id, const int* __restrict__ eval_from,
    const float* __restrict__ emb,
    const int* __restrict__ lengths, const int* __restrict__ maxlen,
    float* __restrict__ mean_emb, float* __restrict__ mask_out)
{
    int bid = blockIdx.x;
    int b = bid >> 4, s = bid & 15;
    int tid = threadIdx.x;
    __shared__ int seqs[TT];
    __shared__ int msk[TT];
    int ml  = maxlen[s];
    int len = lengths[bid];
    int ef  = eval_from[b];
    if (tid < TT) {
        int v;
        if (tid == 0) v = BOS_ID;
        else { int it = item_id[bid * II + tid - 1]; v = it > 0 ? it : 0; }
        if (tid > ml) v = 0;
        int m = (v != 0) && !(tid == len && len > 0);
        seqs[tid] = v;
        msk[tid]  = m;
        mask_out[bid * TT + tid] = (m && (s >= ef)) ? 1.0f : 0.0f;
    }
    __syncthreads();
    int cnt = 0;
    for (int p = 0; p < TT; ++p) cnt += msk[p];
    float acc = 0.0f;
    int d = tid;
    for (int p = 0; p < TT; ++p) {
        if (msk[p]) acc += emb[seqs[p] * DD + d];
    }
    mean_emb[bid * DD + d] = acc / (float)max(cnt, 1);
}

// ============ kernel 3a: gi = me @ wih^T + bih ============
__global__ __launch_bounds__(384, 1) void gi_kernel(
    const float* __restrict__ me_all, const unsigned int* __restrict__ wihP,
    const float* __restrict__ bih, float* __restrict__ gi_all)
{
    __shared__ __align__(16) unsigned int wl[64 * 384];   // 96 KB
    __shared__ __align__(16) float me[DD];
    int t   = threadIdx.x;
    int blk = blockIdx.x;
    {
        const unsigned char* g = (const unsigned char*)wihP + t * 16;
        unsigned char* l = (unsigned char*)wl + t * 16;
#pragma unroll
        for (int i = 0; i < 16; ++i) gld16(g + i * 6144, l + i * 6144);
    }
    float bi = bih[t];
    asm volatile("s_waitcnt vmcnt(0)" ::: "memory");
    __syncthreads();
    for (int q = 0; q < 16; ++q) {
        int bs = blk * 16 + q;
        if (t < DD) me[t] = me_all[bs * DD + t];
        __syncthreads();
        float acc = bi;
#pragma unroll
        for (int dd = 0; dd < 64; ++dd) {
            unsigned int u = wl[dd * 384 + t];
            float f0 = __builtin_bit_cast(float, u << 16);
            float f1 = __builtin_bit_cast(float, u & 0xffff0000u);
            acc += f0 * me[2 * dd] + f1 * me[2 * dd + 1];
        }
        gi_all[bs * 384 + t] = acc;
        __syncthreads();
    }
}

// ============ kernel 3b: sequential GRU (gh, hb) ============
__global__ __launch_bounds__(512, 1) void gru_kernel(
    const unsigned int* __restrict__ wgruP, const float* __restrict__ bhh,
    const float* __restrict__ fus_b, const float* __restrict__ gi_all,
    float* __restrict__ hB)
{
    __shared__ __align__(16) unsigned int wl[64 * 512];   // 128 KB
    __shared__ float h[DD];
    __shared__ float g_z[DD], g_inn[DD], g_hn[DD];
    int t = threadIdx.x;
    int b = blockIdx.x;
    int j = t & 127;
    int grp = t >> 7;      // 0=r, 1=z, 2=n, 3=hb
    {
        const unsigned char* g = (const unsigned char*)wgruP + t * 16;
        unsigned char* l = (unsigned char*)wl + t * 16;
#pragma unroll
        for (int i = 0; i < 16; ++i) gld16(g + i * 8192, l + i * 8192);
    }
    float bias = (t < 384) ? bhh[t] : fus_b[j];
    if (t < DD) h[t] = 0.0f;
    asm volatile("s_waitcnt vmcnt(0)" ::: "memory");
    __syncthreads();
    for (int s = 0; s < SS; ++s) {
        float gi = (grp < 3) ? gi_all[(b * SS + s) * 384 + t] : 0.0f;
        float acc = bias;
#pragma unroll
        for (int dd = 0; dd < 64; ++dd) {
            unsigned int u = wl[dd * 512 + t];
            float f0 = __builtin_bit_cast(float, u << 16);
            float f1 = __builtin_bit_cast(float, u & 0xffff0000u);
            acc += f0 * h[2 * dd] + f1 * h[2 * dd + 1];
        }
        if (grp == 3) {
            hB[(s * BB + b) * DD + j] = acc;          // h BEFORE update; fus_b included
        } else if (grp == 1) { g_z[j] = gi + acc; }
        else if (grp == 2)   { g_inn[j] = gi; g_hn[j] = acc; }
        __syncthreads();
        if (grp == 0) {
            float r = 1.0f / (1.0f + expf(-(gi + acc)));
            float z = 1.0f / (1.0f + expf(-g_z[j]));
            float n = tanhf(g_inn[j] + r * g_hn[j]);
            h[j] = (1.0f - z) * n + z * h[j];
        }
        __syncthreads();
    }
}

// ============ kernel 4: MFMA TCN + fusion (v9 = round-4 skeleton + fold + packed epi) ============
// 2 tiles per block, 4 waves: wave = (tile t = wv>>1, co-half nh = wv&1).
// Per wave: acc[5][4]; chunked K (32 ci per chunk); private ring-2 weight
// staging via global_load_lds with counted vmcnt(4).
// Conv layers: mfma(W, x) -> D[co][p]; epilogue packs 4 co via cvt_pk -> b64 write.
// Fusion:      mfma(x, W) -> D[p][co]; coalesced global writeout.
// Residual folded into tap-2 weights (identity) -> epilogue is write-only.
__global__ __launch_bounds__(256, 2) void tcn_kernel(
    const int* __restrict__ item_id, const float* __restrict__ emb,
    const int* __restrict__ maxlen,
    const unsigned short* __restrict__ wB2,
    const float* __restrict__ cb0, const float* __restrict__ cb1,
    const float* __restrict__ cb2,
    const float* __restrict__ hB, float* __restrict__ reps)
{
    __shared__ __align__(16) unsigned char lds_x[2][XT];      // 44384 B
    __shared__ __align__(16) unsigned char ring[4][2][4096];  // 32768 B
    __shared__ int seqs2[2][TT];

    const int tid = threadIdx.x, bid = blockIdx.x;
    const int lane = tid & 63, wv = tid >> 6;
    const int l15 = lane & 15, q4 = lane >> 4;
    const int t = wv >> 1, nh = wv & 1;
    const int tile = bid * 2 + t;
    const int b = tile >> 4, s = tile & 15;
    const int ml = maxlen[s];

    const unsigned char* wsrc = (const unsigned char*)wB2 + nh * 4096 + lane * 16;
    unsigned char* xb = lds_x[t];

    // prologue: stage chunks 0 and 1 into ring slots 0/1 (wave-private halves)
    {
#pragma unroll
        for (int i = 0; i < 4; ++i) gld16(wsrc + i * 1024, &ring[wv][0][i * 1024]);
#pragma unroll
        for (int i = 0; i < 4; ++i) gld16(wsrc + 8192 + i * 1024, &ring[wv][1][i * 1024]);
    }

    if (tid < 2 * TT) {
        int tt = tid / TT, p = tid - tt * TT;
        int tl = bid * 2 + tt;
        int v;
        if (p == 0) v = BOS_ID;
        else { int it = item_id[tl * II + p - 1]; v = it > 0 ? it : 0; }
        if (p > maxlen[tl & 15]) v = 0;
        seqs2[tt][p] = v;
    }
    // zero guard rows 0..7 of both tiles (608 dwords each = 2432 B)
    for (int i = tid; i < 608; i += 256) {
        *(unsigned int*)(lds_x[0] + i * 4) = 0u;
        *(unsigned int*)(lds_x[1] + i * 4) = 0u;
    }
    __syncthreads();

    // gather embeddings -> x rows 8..72 (bf16 pairs via cvt_pk, padded rows)
    for (int p = nh; p < TT; p += 2) {
        const float* er = emb + (long)seqs2[t][p] * DD + lane * 2;
        float f0 = er[0], f1 = er[1];
        unsigned int pk;
        asm("v_cvt_pk_bf16_f32 %0, %1, %2" : "=v"(pk) : "v"(f0), "v"(f1));
        *(unsigned int*)(xb + (8 + p) * XROW + lane * 4) = pk;
    }
    __syncthreads();

    f32x4 acc[5][4];

#pragma unroll 1
    for (int cid = 0; cid < 40; ++cid) {
        int L = 0, cq, off, kq = 0;
        if (cid < 36) { L = cid / 12; kq = cid - L * 12; int k = kq >> 2; cq = kq & 3; off = (2 - k) << L; }
        else { cq = cid - 36; off = 0; }
        if (cid == 36 || (cid < 36 && kq == 0)) {   // zero acc at layer/fusion start
#pragma unroll
            for (int pt = 0; pt < 5; ++pt)
#pragma unroll
                for (int ct = 0; ct < 4; ++ct)
#pragma unroll
                    for (int r = 0; r < 4; ++r) acc[pt][ct][r] = 0.0f;
        }
        // counted wait: exactly one newer chunk (4 loads) may stay in flight
        if (cid < 39) asm volatile("s_waitcnt vmcnt(4)" ::: "memory");
        else          asm volatile("s_waitcnt vmcnt(0)" ::: "memory");

        const unsigned char* sb = &ring[wv][cid & 1][0];
        short8 wf[4], xf[5];
#pragma unroll
        for (int ct = 0; ct < 4; ++ct)
            wf[ct] = *(const short8*)(sb + q4 * 1024 + (ct * 16 + l15) * 16);
#pragma unroll
        for (int pt = 0; pt < 5; ++pt) {
            int rowA = 8 + pt * 16 + l15 - off;
            xf[pt] = *(const short8*)(xb + rowA * XROW + cq * 64 + q4 * 16);
        }
        // all ds_reads landed before we overwrite this slot with chunk cid+2
        asm volatile("s_waitcnt lgkmcnt(0)" ::: "memory");
        __builtin_amdgcn_sched_barrier(0);
        if (cid <= 37) {
            const unsigned char* src = wsrc + (size_t)(cid + 2) * 8192;
#pragma unroll
            for (int i = 0; i < 4; ++i)
                gld16(src + i * 1024, &ring[wv][cid & 1][i * 1024]);
        }

        if (cid < 36) {   // conv: D[co][p] = W · x   (swapped operands)
#pragma unroll
            for (int ct = 0; ct < 4; ++ct)
#pragma unroll
                for (int pt = 0; pt < 5; ++pt)
                    acc[pt][ct] = __builtin_amdgcn_mfma_f32_16x16x32_bf16(
                        wf[ct], xf[pt], acc[pt][ct], 0, 0, 0);
        } else {          // fusion: D[p][co] = x · W
#pragma unroll
            for (int nt = 0; nt < 4; ++nt)
#pragma unroll
                for (int pt = 0; pt < 5; ++pt)
                    acc[pt][nt] = __builtin_amdgcn_mfma_f32_16x16x32_bf16(
                        xf[pt], wf[nt], acc[pt][nt], 0, 0, 0);
        }

        if (cid < 36 && kq == 11) {   // layer epilogue: relu(acc+bias) -> x, packed b64
            const float* cb = (L == 0) ? cb0 : ((L == 1) ? cb1 : cb2);
            __syncthreads();          // all reads of current x done (both tile-waves)
#pragma unroll
            for (int ct = 0; ct < 4; ++ct) {
                f32x4 b4 = *(const f32x4*)(cb + nh * 64 + ct * 16 + q4 * 4);
#pragma unroll
                for (int pt = 0; pt < 5; ++pt) {
                    int p = pt * 16 + l15;
                    if (p < TT) {
                        float v0 = acc[pt][ct][0] + b4[0]; v0 = v0 > 0.f ? v0 : 0.f;
                        float v1 = acc[pt][ct][1] + b4[1]; v1 = v1 > 0.f ? v1 : 0.f;
                        float v2 = acc[pt][ct][2] + b4[2]; v2 = v2 > 0.f ? v2 : 0.f;
                        float v3 = acc[pt][ct][3] + b4[3]; v3 = v3 > 0.f ? v3 : 0.f;
                        unsigned int lo, hi;
                        asm("v_cvt_pk_bf16_f32 %0, %1, %2" : "=v"(lo) : "v"(v0), "v"(v1));
                        asm("v_cvt_pk_bf16_f32 %0, %1, %2" : "=v"(hi) : "v"(v2), "v"(v3));
                        uint2 w2; w2.x = lo; w2.y = hi;
                        *(uint2*)(xb + (8 + p) * XROW + nh * 128 + ct * 32 + q4 * 8) = w2;
                    }
                }
            }
            __syncthreads();          // writes visible before next layer's reads
        }
    }

    // fusion writeout: reps[p][co] = (p<=ml) ? acc + hb : 0   (coalesced)
    float hb[4];
#pragma unroll
    for (int nt = 0; nt < 4; ++nt)
        hb[nt] = hB[(s * BB + b) * DD + nh * 64 + nt * 16 + l15];
    long ob = (long)tile * (TT * DD);
#pragma unroll
    for (int mt = 0; mt < 5; ++mt)
#pragma unroll
        for (int nt = 0; nt < 4; ++nt)
#pragma unroll
            for (int r = 0; r < 4; ++r) {
                int p = mt * 16 + q4 * 4 + r;
                if (p < TT) {
                    float v = (p <= ml) ? (acc[mt][nt][r] + hb[nt]) : 0.0f;
                    reps[ob + p * DD + nh * 64 + nt * 16 + l15] = v;
                }
            }
}

extern "C" void kernel_launch(void* const* d_in, const int* in_sizes, int n_in,
                              void* d_out, int out_size, void* d_ws, size_t ws_size,
                              hipStream_t stream) {
    const int*   item_id   = (const int*)  d_in[0];
    const int*   eval_from = (const int*)  d_in[1];
    const int*   u_type    = (const int*)  d_in[2];
    const float* emb       = (const float*)d_in[3];
    const float* conv_w0   = (const float*)d_in[4];
    const float* conv_b0   = (const float*)d_in[5];
    const float* conv_w1   = (const float*)d_in[6];
    const float* conv_b1   = (const float*)d_in[7];
    const float* conv_w2   = (const float*)d_in[8];
    const float* conv_b2   = (const float*)d_in[9];
    const float* gru_wih   = (const float*)d_in[10];
    const float* gru_whh   = (const float*)d_in[11];
    const float* gru_bih   = (const float*)d_in[12];
    const float* gru_bhh   = (const float*)d_in[13];
    const float* fus_w     = (const float*)d_in[14];
    const float* fus_b     = (const float*)d_in[15];

    char* ws = (char*)d_ws;
    int*            lengths  = (int*)           (ws + OFF_LEN);
    int*            maxlen   = (int*)           (ws + OFF_ML);
    float*          mean_emb = (float*)         (ws + OFF_ME);
    float*          hB       = (float*)         (ws + OFF_HB);
    unsigned short* wB2      = (unsigned short*)(ws + OFF_WB2);
    unsigned int*   wihP     = (unsigned int*)  (ws + OFF_WIHP);
    unsigned int*   wgruP    = (unsigned int*)  (ws + OFF_WGRU);
    float*          gi_all   = (float*)         (ws + OFF_GI);

    float* out  = (float*)d_out;
    float* reps = out;
    float* mout = out + OUT_MASK;
    float* uout = out + OUT_UTYPE;

    prep_kernel<<<864, 256, 0, stream>>>(conv_w0, conv_w1, conv_w2, fus_w,
                                         gru_wih, gru_whh, wB2, wihP, wgruP);
    len_kernel<<<SS, 256, 0, stream>>>(item_id, u_type, lengths, maxlen, uout);
    mean_kernel<<<BB * SS, 128, 0, stream>>>(item_id, eval_from, emb, lengths, maxlen,
                                             mean_emb, mout);
    gi_kernel<<<BB, 384, 0, stream>>>(mean_emb, wihP, gru_bih, gi_all);
    gru_kernel<<<BB, 512, 0, stream>>>(wgruP, gru_bhh, fus_b, gi_all, hB);
    tcn_kernel<<<BB * SS / 2, 256, 0, stream>>>(item_id, emb, maxlen, wB2,
                                                conv_b0, conv_b1, conv_b2, hB, reps);
}

// Round 12
// 267.535 us; speedup vs baseline: 1.6880x; 1.1375x over previous
//
#include <hip/hip_runtime.h>

#define BB 256
#define SS 16
#define II 64
#define DD 128
#define TT 65            // I + 1 (BOS prepended)
#define BOS_ID 100000
#define XROW 256         // x row stride: 128 bf16, XOR-16B swizzled (byte ^= (row&7)<<4)
#define XROWS 73         // 8 zero guard rows + 65 positions
#define XT (XROWS*XROW)  // 18688 B per tile

// ---------------- ws layout (bytes) ----------------
#define OFF_LEN  0                        // int lengths[B][S]            16384
#define OFF_ML   16384                    // int maxlen[S]                64
#define OFF_ME   32768                    // float mean_emb[B][S][D]      2 MB
#define OFF_HB   (32768 + 2097152)        // float hB[S][B][D]            2 MB
#define OFF_WB2  (OFF_HB + 2097152)       // bf16 wB2[80 half-chunks][2048]  327680
#define OFF_WIHP (OFF_WB2 + 327680)       // u32 wihP[64][384]            98304
#define OFF_WGRU (OFF_WIHP + 98304)       // u32 wgruP[64][512]           131072
#define OFF_GI   (OFF_WGRU + 131072)      // float gi[4096][384]          6291456

// ---------------- out layout (float elements) ----------------
#define OUT_MASK  (BB*SS*TT*DD)          // 34,078,720
#define OUT_UTYPE (OUT_MASK + BB*SS*TT)

typedef __attribute__((ext_vector_type(8))) short short8;
typedef __attribute__((ext_vector_type(4))) float f32x4;

__device__ __forceinline__ unsigned short f2bf(float f) {
    unsigned int u = __builtin_bit_cast(unsigned int, f);
    return (unsigned short)((u + 0x7fffu + ((u >> 16) & 1u)) >> 16);  // RNE
}
__device__ __forceinline__ void gld16(const void* g, void* l) {
    __builtin_amdgcn_global_load_lds(
        (const __attribute__((address_space(1))) void*)g,
        (__attribute__((address_space(3))) void*)l, 16, 0, 0);
}

// ============ kernel 0: weight prep ============
// Conv + fusion weights -> wB2, 80 half-chunks of 4 KB; full chunk cid = 8 KB:
//   cid = (L*3+k)*4+cq for conv (0..35), 36+cq for fusion.
//   half (nh) layout [g 0..3][c 0..63][e 0..7] bf16: W[co=nh*64+c][ci=cq*32+g*8+e].
//   RESIDUAL TRICK: identity added to tap k=2 (off=0) of every conv layer,
//   so conv(x)+x is a single GEMM (epilogue never re-reads x).
__global__ __launch_bounds__(256) void prep_kernel(
    const float* __restrict__ w0, const float* __restrict__ w1,
    const float* __restrict__ w2, const float* __restrict__ fus_w,
    const float* __restrict__ wih, const float* __restrict__ whh,
    unsigned short* __restrict__ wB2,
    unsigned int* __restrict__ wihP, unsigned int* __restrict__ wgruP)
{
    int idx = blockIdx.x * 256 + threadIdx.x;
    if (idx < 163840) {
        int cid2  = idx >> 11;           // 0..79
        int inner = idx & 2047;
        int g = inner >> 9;
        int c = (inner >> 3) & 63;
        int e = inner & 7;
        int nh   = cid2 & 1;
        int rest = cid2 >> 1;            // 0..39
        int cq   = rest & 3;
        int m    = rest >> 2;            // 0..8 conv, 9 fusion
        int ci = cq * 32 + g * 8 + e;
        int co = nh * 64 + c;
        float v;
        if (m < 9) {
            int L = m / 3, k = m % 3;
            const float* w = (L == 0) ? w0 : ((L == 1) ? w1 : w2);
            v = w[(co * 128 + ci) * 3 + k];
            if (k == 2 && ci == co) v += 1.0f;   // fold residual into GEMM
        } else {
            v = fus_w[co * 256 + ci];    // tc half of fus_w
        }
        wB2[idx] = f2bf(v);
    } else if (idx < 163840 + 24576) {
        int f  = idx - 163840;
        int dd = f / 384;
        int r  = f % 384;
        unsigned int lo = f2bf(wih[r * 128 + 2 * dd]);
        unsigned int hi = f2bf(wih[r * 128 + 2 * dd + 1]);
        wihP[f] = (hi << 16) | lo;
    } else if (idx < 163840 + 24576 + 32768) {
        int f  = idx - 163840 - 24576;
        int dd = f >> 9;
        int r  = f & 511;
        float v0, v1;
        if (r < 384) { v0 = whh[r * 128 + 2 * dd]; v1 = whh[r * 128 + 2 * dd + 1]; }
        else { const float* fw = fus_w + (r - 384) * 256 + 128;
               v0 = fw[2 * dd]; v1 = fw[2 * dd + 1]; }
        wgruP[f] = ((unsigned int)f2bf(v1) << 16) | (unsigned int)f2bf(v0);
    }
}

// ============ kernel 1: lengths, per-s max, u_type ============
__global__ __launch_bounds__(256) void len_kernel(
    const int* __restrict__ item_id, const int* __restrict__ u_type,
    int* __restrict__ lengths, int* __restrict__ maxlen,
    float* __restrict__ u_out)
{
    int s = blockIdx.x;
    int b = threadIdx.x;
    const int* row = item_id + (b * SS + s) * II;
    int cnt = 0;
    for (int i = 0; i < II; ++i) cnt += (row[i] > 0);
    lengths[b * SS + s] = cnt;
    __shared__ int red[256];
    red[b] = cnt;
    __syncthreads();
    for (int off = 128; off > 0; off >>= 1) {
        if (b < off) red[b] = max(red[b], red[b + off]);
        __syncthreads();
    }
    if (b == 0) maxlen[s] = red[0];
    if (s == 0) u_out[b] = (float)u_type[b];
}

// ============ kernel 2: masks + mean_emb ============
__global__ __launch_bounds__(128) void mean_kernel(
    const int* __restrict__ item_id, const int* __restrict__ eval_from,
    const float* __restrict__ emb,
    const int* __restrict__ lengths, const int* __restrict__ maxlen,
    float* __restrict__ mean_emb, float* __restrict__ mask_out)
{
    int bid = blockIdx.x;
    int b = bid >> 4, s = bid & 15;
    int tid = threadIdx.x;
    __shared__ int seqs[TT];
    __shared__ int msk[TT];
    int ml  = maxlen[s];
    int len = lengths[bid];
    int ef  = eval_from[b];
    if (tid < TT) {
        int v;
        if (tid == 0) v = BOS_ID;
        else { int it = item_id[bid * II + tid - 1]; v = it > 0 ? it : 0; }
        if (tid > ml) v = 0;
        int m = (v != 0) && !(tid == len && len > 0);
        seqs[tid] = v;
        msk[tid]  = m;
        mask_out[bid * TT + tid] = (m && (s >= ef)) ? 1.0f : 0.0f;
    }
    __syncthreads();
    int cnt = 0;
    for (int p = 0; p < TT; ++p) cnt += msk[p];
    float acc = 0.0f;
    int d = tid;
    for (int p = 0; p < TT; ++p) {
        if (msk[p]) acc += emb[seqs[p] * DD + d];
    }
    mean_emb[bid * DD + d] = acc / (float)max(cnt, 1);
}

// ============ kernel 3a: gi = me @ wih^T + bih ============
__global__ __launch_bounds__(384, 1) void gi_kernel(
    const float* __restrict__ me_all, const unsigned int* __restrict__ wihP,
    const float* __restrict__ bih, float* __restrict__ gi_all)
{
    __shared__ __align__(16) unsigned int wl[64 * 384];   // 96 KB
    __shared__ __align__(16) float me[DD];
    int t   = threadIdx.x;
    int blk = blockIdx.x;
    {
        const unsigned char* g = (const unsigned char*)wihP + t * 16;
        unsigned char* l = (unsigned char*)wl + t * 16;
#pragma unroll
        for (int i = 0; i < 16; ++i) gld16(g + i * 6144, l + i * 6144);
    }
    float bi = bih[t];
    asm volatile("s_waitcnt vmcnt(0)" ::: "memory");
    __syncthreads();
    for (int q = 0; q < 16; ++q) {
        int bs = blk * 16 + q;
        if (t < DD) me[t] = me_all[bs * DD + t];
        __syncthreads();
        float acc = bi;
#pragma unroll
        for (int dd = 0; dd < 64; ++dd) {
            unsigned int u = wl[dd * 384 + t];
            float f0 = __builtin_bit_cast(float, u << 16);
            float f1 = __builtin_bit_cast(float, u & 0xffff0000u);
            acc += f0 * me[2 * dd] + f1 * me[2 * dd + 1];
        }
        gi_all[bs * 384 + t] = acc;
        __syncthreads();
    }
}

// ============ kernel 3b: sequential GRU (gh, hb) ============
__global__ __launch_bounds__(512, 1) void gru_kernel(
    const unsigned int* __restrict__ wgruP, const float* __restrict__ bhh,
    const float* __restrict__ fus_b, const float* __restrict__ gi_all,
    float* __restrict__ hB)
{
    __shared__ __align__(16) unsigned int wl[64 * 512];   // 128 KB
    __shared__ float h[DD];
    __shared__ float g_z[DD], g_inn[DD], g_hn[DD];
    int t = threadIdx.x;
    int b = blockIdx.x;
    int j = t & 127;
    int grp = t >> 7;      // 0=r, 1=z, 2=n, 3=hb
    {
        const unsigned char* g = (const unsigned char*)wgruP + t * 16;
        unsigned char* l = (unsigned char*)wl + t * 16;
#pragma unroll
        for (int i = 0; i < 16; ++i) gld16(g + i * 8192, l + i * 8192);
    }
    float bias = (t < 384) ? bhh[t] : fus_b[j];
    if (t < DD) h[t] = 0.0f;
    asm volatile("s_waitcnt vmcnt(0)" ::: "memory");
    __syncthreads();
    for (int s = 0; s < SS; ++s) {
        float gi = (grp < 3) ? gi_all[(b * SS + s) * 384 + t] : 0.0f;
        float acc = bias;
#pragma unroll
        for (int dd = 0; dd < 64; ++dd) {
            unsigned int u = wl[dd * 512 + t];
            float f0 = __builtin_bit_cast(float, u << 16);
            float f1 = __builtin_bit_cast(float, u & 0xffff0000u);
            acc += f0 * h[2 * dd] + f1 * h[2 * dd + 1];
        }
        if (grp == 3) {
            hB[(s * BB + b) * DD + j] = acc;          // h BEFORE update; fus_b included
        } else if (grp == 1) { g_z[j] = gi + acc; }
        else if (grp == 2)   { g_inn[j] = gi; g_hn[j] = acc; }
        __syncthreads();
        if (grp == 0) {
            float r = 1.0f / (1.0f + expf(-(gi + acc)));
            float z = 1.0f / (1.0f + expf(-g_z[j]));
            float n = tanhf(g_inn[j] + r * g_hn[j]);
            h[j] = (1.0f - z) * n + z * h[j];
        }
        __syncthreads();
    }
}

// ============ kernel 4: MFMA TCN + fusion (v12 = v11 + explicit vmcnt drain) ============
// 2 tiles per block, 4 waves: wave = (tile t = wv>>1, co-half nh = wv&1).
// Per wave: acc[5][4] (round-4 orientation: D[p][co]).
// x tiles: 256-B rows, XOR-16B swizzle (byte ^= (row&7)<<4), 8 guard rows.
// Weights: SHARED ring-2 of 8 KB chunks; each wave stages a 2x1 KB slice.
// Per chunk: EXPLICIT s_waitcnt vmcnt(0) (drain own staging loads) BEFORE the
// __syncthreads that publishes the slot — do NOT rely on the barrier draining
// vmcnt for global_load_lds (v10/v11 bug). Prefetch of chunk cid+1 still
// overlaps chunk cid's full read+MFMA section.
// seqs lives transiently in ring[1]. Residual folded into tap-2 weights.
// LDS = 53,760 B -> 3 blocks/CU (12 waves/CU, 3/SIMD).
__global__ __launch_bounds__(256, 3) void tcn_kernel(
    const int* __restrict__ item_id, const float* __restrict__ emb,
    const int* __restrict__ maxlen,
    const unsigned short* __restrict__ wB2,
    const float* __restrict__ cb0, const float* __restrict__ cb1,
    const float* __restrict__ cb2,
    const float* __restrict__ hB, float* __restrict__ reps)
{
    __shared__ __align__(16) unsigned char lds_x[2][XT];   // 37376 B
    __shared__ __align__(16) unsigned char ring[2][8192];  // 16384 B -> 53760 total

    const int tid = threadIdx.x, bid = blockIdx.x;
    const int lane = tid & 63, wv = tid >> 6;
    const int l15 = lane & 15, q4 = lane >> 4;
    const int t = wv >> 1, nh = wv & 1;
    const int tile = bid * 2 + t;
    const int b = tile >> 4, s = tile & 15;
    const int ml = maxlen[s];

    const unsigned char* wgbase = (const unsigned char*)wB2;
    unsigned char* xb = lds_x[t];

    // cooperative stage of chunk 0 -> ring[0]; per-wave slice, uniform dst
    {
        const unsigned char* src = wgbase + wv * 1024 + lane * 16;
        gld16(src,        &ring[0][wv * 1024]);
        gld16(src + 4096, &ring[0][4096 + wv * 1024]);
    }
    // transient seqs in ring[1] (free until chunk 1 is staged)
    int* seqs2 = (int*)&ring[1][0];
    if (tid < 2 * TT) {
        int tt = tid / TT, p = tid - tt * TT;
        int tl = bid * 2 + tt;
        int v;
        if (p == 0) v = BOS_ID;
        else { int it = item_id[tl * II + p - 1]; v = it > 0 ? it : 0; }
        if (p > maxlen[tl & 15]) v = 0;
        seqs2[tt * TT + p] = v;
    }
    // zero guard rows 0..7 of both tiles (2048 B each)
    {
        float4 z = {0.f, 0.f, 0.f, 0.f};
        if (tid < 128) *(float4*)(lds_x[0] + tid * 16) = z;
        else           *(float4*)(lds_x[1] + (tid - 128) * 16) = z;
    }
    __syncthreads();

    // gather embeddings -> rows 8..72 of own tile (bf16 pairs, swizzled);
    // the two nh-waves of a tile split rows by parity.
    for (int p = nh; p < TT; p += 2) {
        const float* er = emb + (long)seqs2[t * TT + p] * DD + lane * 2;
        float f0 = er[0], f1 = er[1];
        unsigned int pk = ((unsigned int)f2bf(f1) << 16) | (unsigned int)f2bf(f0);
        *(unsigned int*)(xb + (8 + p) * XROW + ((lane * 4) ^ ((p & 7) << 4))) = pk;
    }

    f32x4 acc[5][4];

#pragma unroll 1
    for (int cid = 0; cid < 40; ++cid) {
        int L = 0, cq, off, kq = 0;
        if (cid < 36) { L = cid / 12; kq = cid - L * 12; int k = kq >> 2; cq = kq & 3; off = (2 - k) << L; }
        else { cq = cid - 36; off = 0; }
        if (cid == 36 || (cid < 36 && kq == 0)) {   // zero acc at layer/fusion start
#pragma unroll
            for (int mt = 0; mt < 5; ++mt)
#pragma unroll
                for (int nt = 0; nt < 4; ++nt)
#pragma unroll
                    for (int r = 0; r < 4; ++r) acc[mt][nt][r] = 0.0f;
        }
        // EXPLICIT drain of this wave's staging loads (chunk cid), THEN the
        // barrier publishes all 4 waves' slices of slot cid&1 and guards
        // slot (cid+1)&1 reuse (everyone's reads drained via lgkmcnt).
        asm volatile("s_waitcnt vmcnt(0)" ::: "memory");
        __syncthreads();

        if (cid <= 38) {   // cooperative stage of chunk cid+1 (uniform dst per wave)
            const unsigned char* src =
                wgbase + (size_t)(cid + 1) * 8192 + wv * 1024 + lane * 16;
            gld16(src,        &ring[(cid + 1) & 1][wv * 1024]);
            gld16(src + 4096, &ring[(cid + 1) & 1][4096 + wv * 1024]);
        }

        const unsigned char* sb = &ring[cid & 1][nh * 4096];
        const int xmask = ((l15 - off) & 7) << 4;          // uniform across mt
        const int colx  = (cq * 64 + q4 * 16) ^ xmask;
        short8 bfr[4], af[5];
#pragma unroll
        for (int nt = 0; nt < 4; ++nt)
            bfr[nt] = *(const short8*)(sb + q4 * 1024 + (nt * 16 + l15) * 16);
#pragma unroll
        for (int mt = 0; mt < 5; ++mt) {
            int rowA = 8 + mt * 16 + l15 - off;
            af[mt] = *(const short8*)(xb + rowA * XROW + colx);
        }
#pragma unroll
        for (int nt = 0; nt < 4; ++nt)
#pragma unroll
            for (int mt = 0; mt < 5; ++mt)
                acc[mt][nt] = __builtin_amdgcn_mfma_f32_16x16x32_bf16(
                    af[mt], bfr[nt], acc[mt][nt], 0, 0, 0);

        if (cid < 36 && kq == 11) {   // layer epilogue: relu(acc+bias) -> x (write-only)
            const float* cb = (L == 0) ? cb0 : ((L == 1) ? cb1 : cb2);
            __syncthreads();          // all reads of current x done
#pragma unroll
            for (int nt = 0; nt < 4; ++nt) {
                float bia = cb[nh * 64 + nt * 16 + l15];
                int cbyte = nh * 128 + nt * 32 + l15 * 2;
#pragma unroll
                for (int mt = 0; mt < 5; ++mt)
#pragma unroll
                    for (int r = 0; r < 4; ++r) {
                        int p = mt * 16 + q4 * 4 + r;
                        if (p < TT) {
                            int row = 8 + p;
                            float v = acc[mt][nt][r] + bia;
                            *(unsigned short*)(xb + row * XROW +
                                               (cbyte ^ ((row & 7) << 4))) =
                                f2bf(v > 0.f ? v : 0.f);
                        }
                    }
            }
            __syncthreads();          // writes visible before next layer's reads
        }
    }

    // fusion writeout: reps[p][co] = (p<=ml) ? acc + hb : 0   (coalesced)
    float hb[4];
#pragma unroll
    for (int nt = 0; nt < 4; ++nt)
        hb[nt] = hB[(s * BB + b) * DD + nh * 64 + nt * 16 + l15];
    long ob = (long)tile * (TT * DD);
#pragma unroll
    for (int mt = 0; mt < 5; ++mt)
#pragma unroll
        for (int nt = 0; nt < 4; ++nt)
#pragma unroll
            for (int r = 0; r < 4; ++r) {
                int p = mt * 16 + q4 * 4 + r;
                if (p < TT) {
                    float v = (p <= ml) ? (acc[mt][nt][r] + hb[nt]) : 0.0f;
                    reps[ob + p * DD + nh * 64 + nt * 16 + l15] = v;
                }
            }
}

extern "C" void kernel_launch(void* const* d_in, const int* in_sizes, int n_in,
                              void* d_out, int out_size, void* d_ws, size_t ws_size,
                              hipStream_t stream) {
    const int*   item_id   = (const int*)  d_in[0];
    const int*   eval_from = (const int*)  d_in[1];
    const int*   u_type    = (const int*)  d_in[2];
    const float* emb       = (const float*)d_in[3];
    const float* conv_w0   = (const float*)d_in[4];
    const float* conv_b0   = (const float*)d_in[5];
    const float* conv_w1   = (const float*)d_in[6];
    const float* conv_b1   = (const float*)d_in[7];
    const float* conv_w2   = (const float*)d_in[8];
    const float* conv_b2   = (const float*)d_in[9];
    const float* gru_wih   = (const float*)d_in[10];
    const float* gru_whh   = (const float*)d_in[11];
    const float* gru_bih   = (const float*)d_in[12];
    const float* gru_bhh   = (const float*)d_in[13];
    const float* fus_w     = (const float*)d_in[14];
    const float* fus_b     = (const float*)d_in[15];

    char* ws = (char*)d_ws;
    int*            lengths  = (int*)           (ws + OFF_LEN);
    int*            maxlen   = (int*)           (ws + OFF_ML);
    float*          mean_emb = (float*)         (ws + OFF_ME);
    float*          hB       = (float*)         (ws + OFF_HB);
    unsigned short* wB2      = (unsigned short*)(ws + OFF_WB2);
    unsigned int*   wihP     = (unsigned int*)  (ws + OFF_WIHP);
    unsigned int*   wgruP    = (unsigned int*)  (ws + OFF_WGRU);
    float*          gi_all   = (float*)         (ws + OFF_GI);

    float* out  = (float*)d_out;
    float* reps = out;
    float* mout = out + OUT_MASK;
    float* uout = out + OUT_UTYPE;

    prep_kernel<<<864, 256, 0, stream>>>(conv_w0, conv_w1, conv_w2, fus_w,
                                         gru_wih, gru_whh, wB2, wihP, wgruP);
    len_kernel<<<SS, 256, 0, stream>>>(item_id, u_type, lengths, maxlen, uout);
    mean_kernel<<<BB * SS, 128, 0, stream>>>(item_id, eval_from, emb, lengths, maxlen,
                                             mean_emb, mout);
    gi_kernel<<<BB, 384, 0, stream>>>(mean_emb, wihP, gru_bih, gi_all);
    gru_kernel<<<BB, 512, 0, stream>>>(wgruP, gru_bhh, fus_b, gi_all, hB);
    tcn_kernel<<<BB * SS / 2, 256, 0, stream>>>(item_id, emb, maxlen, wB2,
                                                conv_b0, conv_b1, conv_b2, hB, reps);
}

// Round 13
// 257.427 us; speedup vs baseline: 1.7542x; 1.0393x over previous
//
#include <hip/hip_runtime.h>

#define BB 256
#define SS 16
#define II 64
#define DD 128
#define TT 65            // I + 1 (BOS prepended)
#define BOS_ID 100000
#define XROW 256         // x row stride: 128 bf16, XOR-16B swizzled (byte ^= (row&7)<<4)
#define XROWS 73         // 8 zero guard rows + 65 positions
#define XT (XROWS*XROW)  // 18688 B per tile

// ---------------- ws layout (bytes) ----------------
#define OFF_LEN  0                        // int lengths[B][S]            16384
#define OFF_ML   16384                    // int maxlen[S]                64
#define OFF_ME   32768                    // float mean_emb[B][S][D]      2 MB
#define OFF_HB   (32768 + 2097152)        // float hB[S][B][D]            2 MB
#define OFF_WB2  (OFF_HB + 2097152)       // bf16 wB2[80 half-chunks][2048]  327680
#define OFF_WIHP (OFF_WB2 + 327680)       // u32 wih4[16][384][4]         98304
#define OFF_WGRU (OFF_WIHP + 98304)       // u32 wgru4[16][512][4]        131072
#define OFF_GI   (OFF_WGRU + 131072)      // float gi[4096][384]          6291456

// ---------------- out layout (float elements) ----------------
#define OUT_MASK  (BB*SS*TT*DD)          // 34,078,720
#define OUT_UTYPE (OUT_MASK + BB*SS*TT)

typedef __attribute__((ext_vector_type(8))) short short8;
typedef __attribute__((ext_vector_type(4))) float f32x4;

__device__ __forceinline__ unsigned short f2bf(float f) {
    unsigned int u = __builtin_bit_cast(unsigned int, f);
    return (unsigned short)((u + 0x7fffu + ((u >> 16) & 1u)) >> 16);  // RNE
}
__device__ __forceinline__ float bflo(unsigned int u) {
    return __builtin_bit_cast(float, u << 16);
}
__device__ __forceinline__ float bfhi(unsigned int u) {
    return __builtin_bit_cast(float, u & 0xffff0000u);
}
__device__ __forceinline__ void gld16(const void* g, void* l) {
    __builtin_amdgcn_global_load_lds(
        (const __attribute__((address_space(1))) void*)g,
        (__attribute__((address_space(3))) void*)l, 16, 0, 0);
}

// ============ kernel 0: weight prep ============
// Conv + fusion weights -> wB2 (as round 12, identity folded into tap-2).
// wih  -> wih4[dd4][r][c]  u32 = pack(wih[r][8dd4+2c], wih[r][8dd4+2c+1])
// whh/fusB -> wgru4[dd4][r][c] same packing (r<384: whh row r; else fusB row r-384)
__global__ __launch_bounds__(256) void prep_kernel(
    const float* __restrict__ w0, const float* __restrict__ w1,
    const float* __restrict__ w2, const float* __restrict__ fus_w,
    const float* __restrict__ wih, const float* __restrict__ whh,
    unsigned short* __restrict__ wB2,
    unsigned int* __restrict__ wih4, unsigned int* __restrict__ wgru4)
{
    int idx = blockIdx.x * 256 + threadIdx.x;
    if (idx < 163840) {
        int cid2  = idx >> 11;           // 0..79
        int inner = idx & 2047;
        int g = inner >> 9;
        int c = (inner >> 3) & 63;
        int e = inner & 7;
        int nh   = cid2 & 1;
        int rest = cid2 >> 1;            // 0..39
        int cq   = rest & 3;
        int m    = rest >> 2;            // 0..8 conv, 9 fusion
        int ci = cq * 32 + g * 8 + e;
        int co = nh * 64 + c;
        float v;
        if (m < 9) {
            int L = m / 3, k = m % 3;
            const float* w = (L == 0) ? w0 : ((L == 1) ? w1 : w2);
            v = w[(co * 128 + ci) * 3 + k];
            if (k == 2 && ci == co) v += 1.0f;   // fold residual into GEMM
        } else {
            v = fus_w[co * 256 + ci];    // tc half of fus_w
        }
        wB2[idx] = f2bf(v);
    } else if (idx < 163840 + 24576) {
        int f   = idx - 163840;          // [dd4][r][c]: 16 x 384 x 4
        int dd4 = f / 1536;
        int rem = f - dd4 * 1536;
        int r   = rem >> 2;
        int c   = rem & 3;
        int d0  = 8 * dd4 + 2 * c;
        unsigned int lo = f2bf(wih[r * 128 + d0]);
        unsigned int hi = f2bf(wih[r * 128 + d0 + 1]);
        wih4[f] = (hi << 16) | lo;
    } else if (idx < 163840 + 24576 + 32768) {
        int f   = idx - 163840 - 24576;  // [dd4][r][c]: 16 x 512 x 4
        int dd4 = f >> 11;
        int rem = f & 2047;
        int r   = rem >> 2;
        int c   = rem & 3;
        int d0  = 8 * dd4 + 2 * c;
        float v0, v1;
        if (r < 384) { v0 = whh[r * 128 + d0]; v1 = whh[r * 128 + d0 + 1]; }
        else { const float* fw = fus_w + (r - 384) * 256 + 128;
               v0 = fw[d0]; v1 = fw[d0 + 1]; }
        wgru4[f] = ((unsigned int)f2bf(v1) << 16) | (unsigned int)f2bf(v0);
    }
}

// ============ kernel 1: lengths, per-s max, u_type ============
__global__ __launch_bounds__(256) void len_kernel(
    const int* __restrict__ item_id, const int* __restrict__ u_type,
    int* __restrict__ lengths, int* __restrict__ maxlen,
    float* __restrict__ u_out)
{
    int s = blockIdx.x;
    int b = threadIdx.x;
    const int* row = item_id + (b * SS + s) * II;
    int cnt = 0;
    for (int i = 0; i < II; ++i) cnt += (row[i] > 0);
    lengths[b * SS + s] = cnt;
    __shared__ int red[256];
    red[b] = cnt;
    __syncthreads();
    for (int off = 128; off > 0; off >>= 1) {
        if (b < off) red[b] = max(red[b], red[b + off]);
        __syncthreads();
    }
    if (b == 0) maxlen[s] = red[0];
    if (s == 0) u_out[b] = (float)u_type[b];
}

// ============ kernel 2: masks + mean_emb ============
__global__ __launch_bounds__(128) void mean_kernel(
    const int* __restrict__ item_id, const int* __restrict__ eval_from,
    const float* __restrict__ emb,
    const int* __restrict__ lengths, const int* __restrict__ maxlen,
    float* __restrict__ mean_emb, float* __restrict__ mask_out)
{
    int bid = blockIdx.x;
    int b = bid >> 4, s = bid & 15;
    int tid = threadIdx.x;
    __shared__ int seqs[TT];
    __shared__ int msk[TT];
    int ml  = maxlen[s];
    int len = lengths[bid];
    int ef  = eval_from[b];
    if (tid < TT) {
        int v;
        if (tid == 0) v = BOS_ID;
        else { int it = item_id[bid * II + tid - 1]; v = it > 0 ? it : 0; }
        if (tid > ml) v = 0;
        int m = (v != 0) && !(tid == len && len > 0);
        seqs[tid] = v;
        msk[tid]  = m;
        mask_out[bid * TT + tid] = (m && (s >= ef)) ? 1.0f : 0.0f;
    }
    __syncthreads();
    int cnt = 0;
    for (int p = 0; p < TT; ++p) cnt += msk[p];
    float acc = 0.0f;
    int d = tid;
    for (int p = 0; p < TT; ++p) {
        if (msk[p]) acc += emb[seqs[p] * DD + d];
    }
    mean_emb[bid * DD + d] = acc / (float)max(cnt, 1);
}

// ============ kernel 3a: gi = me @ wih^T + bih (b128 weight reads) ============
__global__ __launch_bounds__(384, 1) void gi_kernel(
    const float* __restrict__ me_all, const unsigned int* __restrict__ wih4,
    const float* __restrict__ bih, float* __restrict__ gi_all)
{
    __shared__ __align__(16) unsigned int wl[16 * 384 * 4];   // 96 KB
    __shared__ __align__(16) float me[DD];
    int t   = threadIdx.x;
    int blk = blockIdx.x;
    {
        const unsigned char* g = (const unsigned char*)wih4 + t * 16;
        unsigned char* l = (unsigned char*)wl + t * 16;
#pragma unroll
        for (int i = 0; i < 16; ++i) gld16(g + i * 6144, l + i * 6144);
    }
    float bi = bih[t];
    asm volatile("s_waitcnt vmcnt(0)" ::: "memory");
    __syncthreads();
    const uint4* wl4 = (const uint4*)wl;
    for (int q = 0; q < 16; ++q) {
        int bs = blk * 16 + q;
        if (t < DD) me[t] = me_all[bs * DD + t];
        __syncthreads();
        float acc = bi;
#pragma unroll
        for (int dd4 = 0; dd4 < 16; ++dd4) {
            uint4 u = wl4[dd4 * 384 + t];
            float4 h0 = *(const float4*)&me[8 * dd4];
            float4 h1 = *(const float4*)&me[8 * dd4 + 4];
            acc += bflo(u.x) * h0.x + bfhi(u.x) * h0.y;
            acc += bflo(u.y) * h0.z + bfhi(u.y) * h0.w;
            acc += bflo(u.z) * h1.x + bfhi(u.z) * h1.y;
            acc += bflo(u.w) * h1.z + bfhi(u.w) * h1.w;
        }
        gi_all[bs * 384 + t] = acc;
        __syncthreads();
    }
}

// ============ kernel 3b: sequential GRU (b128 weight reads, float4 h) ============
__global__ __launch_bounds__(512, 1) void gru_kernel(
    const unsigned int* __restrict__ wgru4, const float* __restrict__ bhh,
    const float* __restrict__ fus_b, const float* __restrict__ gi_all,
    float* __restrict__ hB)
{
    __shared__ __align__(16) unsigned int wl[16 * 512 * 4];   // 128 KB
    __shared__ __align__(16) float h[DD];
    __shared__ float g_z[DD], g_inn[DD], g_hn[DD];
    int t = threadIdx.x;
    int b = blockIdx.x;
    int j = t & 127;
    int grp = t >> 7;      // 0=r, 1=z, 2=n, 3=hb
    {
        const unsigned char* g = (const unsigned char*)wgru4 + t * 16;
        unsigned char* l = (unsigned char*)wl + t * 16;
#pragma unroll
        for (int i = 0; i < 16; ++i) gld16(g + i * 8192, l + i * 8192);
    }
    float bias = (t < 384) ? bhh[t] : fus_b[j];
    if (t < DD) h[t] = 0.0f;
    asm volatile("s_waitcnt vmcnt(0)" ::: "memory");
    __syncthreads();
    const uint4* wl4 = (const uint4*)wl;
    for (int s = 0; s < SS; ++s) {
        float gi = (grp < 3) ? gi_all[(b * SS + s) * 384 + t] : 0.0f;
        float acc = bias;
#pragma unroll
        for (int dd4 = 0; dd4 < 16; ++dd4) {
            uint4 u = wl4[dd4 * 512 + t];
            float4 h0 = *(const float4*)&h[8 * dd4];
            float4 h1 = *(const float4*)&h[8 * dd4 + 4];
            acc += bflo(u.x) * h0.x + bfhi(u.x) * h0.y;
            acc += bflo(u.y) * h0.z + bfhi(u.y) * h0.w;
            acc += bflo(u.z) * h1.x + bfhi(u.z) * h1.y;
            acc += bflo(u.w) * h1.z + bfhi(u.w) * h1.w;
        }
        if (grp == 3) {
            hB[(s * BB + b) * DD + j] = acc;          // h BEFORE update; fus_b included
        } else if (grp == 1) { g_z[j] = gi + acc; }
        else if (grp == 2)   { g_inn[j] = gi; g_hn[j] = acc; }
        __syncthreads();
        if (grp == 0) {
            float r = 1.0f / (1.0f + expf(-(gi + acc)));
            float z = 1.0f / (1.0f + expf(-g_z[j]));
            float n = tanhf(g_inn[j] + r * g_hn[j]);
            h[j] = (1.0f - z) * n + z * h[j];
        }
        __syncthreads();
    }
}

// ============ kernel 4: MFMA TCN + fusion (v12, UNCHANGED from round 12) ============
__global__ __launch_bounds__(256, 3) void tcn_kernel(
    const int* __restrict__ item_id, const float* __restrict__ emb,
    const int* __restrict__ maxlen,
    const unsigned short* __restrict__ wB2,
    const float* __restrict__ cb0, const float* __restrict__ cb1,
    const float* __restrict__ cb2,
    const float* __restrict__ hB, float* __restrict__ reps)
{
    __shared__ __align__(16) unsigned char lds_x[2][XT];   // 37376 B
    __shared__ __align__(16) unsigned char ring[2][8192];  // 16384 B -> 53760 total

    const int tid = threadIdx.x, bid = blockIdx.x;
    const int lane = tid & 63, wv = tid >> 6;
    const int l15 = lane & 15, q4 = lane >> 4;
    const int t = wv >> 1, nh = wv & 1;
    const int tile = bid * 2 + t;
    const int b = tile >> 4, s = tile & 15;
    const int ml = maxlen[s];

    const unsigned char* wgbase = (const unsigned char*)wB2;
    unsigned char* xb = lds_x[t];

    // cooperative stage of chunk 0 -> ring[0]; per-wave slice, uniform dst
    {
        const unsigned char* src = wgbase + wv * 1024 + lane * 16;
        gld16(src,        &ring[0][wv * 1024]);
        gld16(src + 4096, &ring[0][4096 + wv * 1024]);
    }
    // transient seqs in ring[1] (free until chunk 1 is staged)
    int* seqs2 = (int*)&ring[1][0];
    if (tid < 2 * TT) {
        int tt = tid / TT, p = tid - tt * TT;
        int tl = bid * 2 + tt;
        int v;
        if (p == 0) v = BOS_ID;
        else { int it = item_id[tl * II + p - 1]; v = it > 0 ? it : 0; }
        if (p > maxlen[tl & 15]) v = 0;
        seqs2[tt * TT + p] = v;
    }
    // zero guard rows 0..7 of both tiles (2048 B each)
    {
        float4 z = {0.f, 0.f, 0.f, 0.f};
        if (tid < 128) *(float4*)(lds_x[0] + tid * 16) = z;
        else           *(float4*)(lds_x[1] + (tid - 128) * 16) = z;
    }
    __syncthreads();

    // gather embeddings -> rows 8..72 of own tile (bf16 pairs, swizzled);
    // the two nh-waves of a tile split rows by parity.
    for (int p = nh; p < TT; p += 2) {
        const float* er = emb + (long)seqs2[t * TT + p] * DD + lane * 2;
        float f0 = er[0], f1 = er[1];
        unsigned int pk = ((unsigned int)f2bf(f1) << 16) | (unsigned int)f2bf(f0);
        *(unsigned int*)(xb + (8 + p) * XROW + ((lane * 4) ^ ((p & 7) << 4))) = pk;
    }

    f32x4 acc[5][4];

#pragma unroll 1
    for (int cid = 0; cid < 40; ++cid) {
        int L = 0, cq, off, kq = 0;
        if (cid < 36) { L = cid / 12; kq = cid - L * 12; int k = kq >> 2; cq = kq & 3; off = (2 - k) << L; }
        else { cq = cid - 36; off = 0; }
        if (cid == 36 || (cid < 36 && kq == 0)) {   // zero acc at layer/fusion start
#pragma unroll
            for (int mt = 0; mt < 5; ++mt)
#pragma unroll
                for (int nt = 0; nt < 4; ++nt)
#pragma unroll
                    for (int r = 0; r < 4; ++r) acc[mt][nt][r] = 0.0f;
        }
        // EXPLICIT drain of this wave's staging loads (chunk cid), THEN the
        // barrier publishes all 4 waves' slices of slot cid&1 and guards
        // slot (cid+1)&1 reuse (everyone's reads drained via lgkmcnt).
        asm volatile("s_waitcnt vmcnt(0)" ::: "memory");
        __syncthreads();

        if (cid <= 38) {   // cooperative stage of chunk cid+1 (uniform dst per wave)
            const unsigned char* src =
                wgbase + (size_t)(cid + 1) * 8192 + wv * 1024 + lane * 16;
            gld16(src,        &ring[(cid + 1) & 1][wv * 1024]);
            gld16(src + 4096, &ring[(cid + 1) & 1][4096 + wv * 1024]);
        }

        const unsigned char* sb = &ring[cid & 1][nh * 4096];
        const int xmask = ((l15 - off) & 7) << 4;          // uniform across mt
        const int colx  = (cq * 64 + q4 * 16) ^ xmask;
        short8 bfr[4], af[5];
#pragma unroll
        for (int nt = 0; nt < 4; ++nt)
            bfr[nt] = *(const short8*)(sb + q4 * 1024 + (nt * 16 + l15) * 16);
#pragma unroll
        for (int mt = 0; mt < 5; ++mt) {
            int rowA = 8 + mt * 16 + l15 - off;
            af[mt] = *(const short8*)(xb + rowA * XROW + colx);
        }
#pragma unroll
        for (int nt = 0; nt < 4; ++nt)
#pragma unroll
            for (int mt = 0; mt < 5; ++mt)
                acc[mt][nt] = __builtin_amdgcn_mfma_f32_16x16x32_bf16(
                    af[mt], bfr[nt], acc[mt][nt], 0, 0, 0);

        if (cid < 36 && kq == 11) {   // layer epilogue: relu(acc+bias) -> x (write-only)
            const float* cb = (L == 0) ? cb0 : ((L == 1) ? cb1 : cb2);
            __syncthreads();          // all reads of current x done
#pragma unroll
            for (int nt = 0; nt < 4; ++nt) {
                float bia = cb[nh * 64 + nt * 16 + l15];
                int cbyte = nh * 128 + nt * 32 + l15 * 2;
#pragma unroll
                for (int mt = 0; mt < 5; ++mt)
#pragma unroll
                    for (int r = 0; r < 4; ++r) {
                        int p = mt * 16 + q4 * 4 + r;
                        if (p < TT) {
                            int row = 8 + p;
                            float v = acc[mt][nt][r] + bia;
                            *(unsigned short*)(xb + row * XROW +
                                               (cbyte ^ ((row & 7) << 4))) =
                                f2bf(v > 0.f ? v : 0.f);
                        }
                    }
            }
            __syncthreads();          // writes visible before next layer's reads
        }
    }

    // fusion writeout: reps[p][co] = (p<=ml) ? acc + hb : 0   (coalesced)
    float hb[4];
#pragma unroll
    for (int nt = 0; nt < 4; ++nt)
        hb[nt] = hB[(s * BB + b) * DD + nh * 64 + nt * 16 + l15];
    long ob = (long)tile * (TT * DD);
#pragma unroll
    for (int mt = 0; mt < 5; ++mt)
#pragma unroll
        for (int nt = 0; nt < 4; ++nt)
#pragma unroll
            for (int r = 0; r < 4; ++r) {
                int p = mt * 16 + q4 * 4 + r;
                if (p < TT) {
                    float v = (p <= ml) ? (acc[mt][nt][r] + hb[nt]) : 0.0f;
                    reps[ob + p * DD + nh * 64 + nt * 16 + l15] = v;
                }
            }
}

extern "C" void kernel_launch(void* const* d_in, const int* in_sizes, int n_in,
                              void* d_out, int out_size, void* d_ws, size_t ws_size,
                              hipStream_t stream) {
    const int*   item_id   = (const int*)  d_in[0];
    const int*   eval_from = (const int*)  d_in[1];
    const int*   u_type    = (const int*)  d_in[2];
    const float* emb       = (const float*)d_in[3];
    const float* conv_w0   = (const float*)d_in[4];
    const float* conv_b0   = (const float*)d_in[5];
    const float* conv_w1   = (const float*)d_in[6];
    const float* conv_b1   = (const float*)d_in[7];
    const float* conv_w2   = (const float*)d_in[8];
    const float* conv_b2   = (const float*)d_in[9];
    const float* gru_wih   = (const float*)d_in[10];
    const float* gru_whh   = (const float*)d_in[11];
    const float* gru_bih   = (const float*)d_in[12];
    const float* gru_bhh   = (const float*)d_in[13];
    const float* fus_w     = (const float*)d_in[14];
    const float* fus_b     = (const float*)d_in[15];

    char* ws = (char*)d_ws;
    int*            lengths  = (int*)           (ws + OFF_LEN);
    int*            maxlen   = (int*)           (ws + OFF_ML);
    float*          mean_emb = (float*)         (ws + OFF_ME);
    float*          hB       = (float*)         (ws + OFF_HB);
    unsigned short* wB2      = (unsigned short*)(ws + OFF_WB2);
    unsigned int*   wih4     = (unsigned int*)  (ws + OFF_WIHP);
    unsigned int*   wgru4    = (unsigned int*)  (ws + OFF_WGRU);
    float*          gi_all   = (float*)         (ws + OFF_GI);

    float* out  = (float*)d_out;
    float* reps = out;
    float* mout = out + OUT_MASK;
    float* uout = out + OUT_UTYPE;

    prep_kernel<<<864, 256, 0, stream>>>(conv_w0, conv_w1, conv_w2, fus_w,
                                         gru_wih, gru_whh, wB2, wih4, wgru4);
    len_kernel<<<SS, 256, 0, stream>>>(item_id, u_type, lengths, maxlen, uout);
    mean_kernel<<<BB * SS, 128, 0, stream>>>(item_id, eval_from, emb, lengths, maxlen,
                                             mean_emb, mout);
    gi_kernel<<<BB, 384, 0, stream>>>(mean_emb, wih4, gru_bih, gi_all);
    gru_kernel<<<BB, 512, 0, stream>>>(wgru4, gru_bhh, fus_b, gi_all, hB);
    tcn_kernel<<<BB * SS / 2, 256, 0, stream>>>(item_id, emb, maxlen, wB2,
                                                conv_b0, conv_b1, conv_b2, hB, reps);
}